// Round 12
// baseline (278.031 us; speedup 1.0000x reference)
//
#include <hip/hip_runtime.h>
#include <math.h>

#define B_   16
#define L_   128
#define O_   128
#define N_   256
#define S_   64
#define U_   32
#define DEL_ 64
#define HID_ 512
#define CH_  288          // N_+U_
#define M_   2048         // B_*L_
#define KD_  288          // GEMM K for the Wg projections
#define CM_BASE (DEL_ + N_*U_)   // 8256
#define NSLICE 32

typedef __bf16 bf16_t;
typedef bf16_t bf16x8 __attribute__((ext_vector_type(8)));
typedef float  f32x4  __attribute__((ext_vector_type(4)));

#define AS1(p) ((const __attribute__((address_space(1))) void*)(unsigned long long)(const void*)(p))
#define AS3(p) ((__attribute__((address_space(3))) void*)(unsigned int)(unsigned long long)(const void*)(p))

__device__ __forceinline__ float silu_f(float x){ return x / (1.f + expf(-x)); }
__device__ __forceinline__ float softplus_f(float x){
  return fmaxf(x, 0.f) + log1pf(expf(-fabsf(x)));
}

// ---------------- prep: Wg->bf16 convert + zero loss acc ----------------
#define CVT_BLOCKS 3465   // ceil(887040/256)
__global__ void k_prep(const float* __restrict__ Wg, bf16_t* __restrict__ Wgbf,
                       float* __restrict__ lossa){
  if (blockIdx.x == 0 && threadIdx.x < 2) lossa[threadIdx.x] = 0.f;
  int i = blockIdx.x*256 + threadIdx.x;
  if (i >= 887040) return;          // 7096320/8
  float4 a = ((const float4*)Wg)[2*i];
  float4 b = ((const float4*)Wg)[2*i+1];
  bf16x8 o;
  o[0]=(bf16_t)a.x; o[1]=(bf16_t)a.y; o[2]=(bf16_t)a.z; o[3]=(bf16_t)a.w;
  o[4]=(bf16_t)b.x; o[5]=(bf16_t)b.y; o[6]=(bf16_t)b.z; o[7]=(bf16_t)b.w;
  ((bf16x8*)Wgbf)[i] = o;
}

// ---------------- mlp1: H = relu(x[:, t<128] @ W0.T + b0), direct-x A load ----------------
__global__ __launch_bounds__(256) void k_mlp1(
    const float* __restrict__ x, const float* __restrict__ W0,
    const float* __restrict__ b0, float* __restrict__ Hh){
  __shared__ __align__(16) float As[32][68];
  __shared__ __align__(16) float Bs[32][68];
  int tid = threadIdx.x, tx = tid & 15, ty = tid >> 4;
  int nt = blockIdx.x, mt = blockIdx.y;
  const float* Bb = W0 + (size_t)nt*64*S_;
  float acc[4][4] = {};
  for (int kk = 0; kk < S_; kk += 32) {
    #pragma unroll
    for (int q = 0; q < 2; q++) {
      int idx = tid + q*256; int row = idx >> 3; int c4 = idx & 7;
      int grow = mt*64 + row;
      const float* ap = x + (size_t)((((grow>>7)<<8) + (grow&127))<<6) + kk + c4*4;
      float4 av = *(const float4*)ap;
      float4 bv = *(const float4*)(Bb + (size_t)row*S_ + kk + c4*4);
      As[c4*4+0][row]=av.x; As[c4*4+1][row]=av.y;
      As[c4*4+2][row]=av.z; As[c4*4+3][row]=av.w;
      Bs[c4*4+0][row]=bv.x; Bs[c4*4+1][row]=bv.y;
      Bs[c4*4+2][row]=bv.z; Bs[c4*4+3][row]=bv.w;
    }
    __syncthreads();
    #pragma unroll
    for (int k = 0; k < 32; k++) {
      float4 a4 = *(const float4*)&As[k][ty*4];
      float4 b4 = *(const float4*)&Bs[k][tx*4];
      float av[4] = {a4.x,a4.y,a4.z,a4.w};
      float bv[4] = {b4.x,b4.y,b4.z,b4.w};
      #pragma unroll
      for (int i=0;i<4;i++)
        #pragma unroll
        for (int j=0;j<4;j++) acc[i][j] += av[i]*bv[j];
    }
    __syncthreads();
  }
  #pragma unroll
  for (int i = 0; i < 4; i++) {
    int m = mt*64 + ty*4 + i;
    float4 v; float* vv = (float*)&v;
    #pragma unroll
    for (int j = 0; j < 4; j++)
      vv[j] = fmaxf(acc[i][j] + b0[nt*64 + tx*4 + j], 0.f);
    *(float4*)(&Hh[(size_t)m*HID_ + nt*64 + tx*4]) = v;
  }
}

// ---------------- fp32 TN GEMM, 32x64 tile (mlp2: 256 blocks) ----------------
__global__ __launch_bounds__(256) void k_gemm_tn_s(
    const float* __restrict__ A, const float* __restrict__ B,
    const float* __restrict__ bias, float* __restrict__ C,
    int M, int N, int K){
  __shared__ __align__(16) float As[32][36];
  __shared__ __align__(16) float Bs[32][68];
  int tid = threadIdx.x, tx = tid & 15, ty = tid >> 4;
  int nt = blockIdx.x, mt = blockIdx.y;
  const float* Ab = A + (size_t)mt*32*K;
  const float* Bb = B + (size_t)nt*64*K;
  float acc[2][4] = {};
  for (int kk = 0; kk < K; kk += 32) {
    { int row = tid >> 3, c4 = tid & 7;
      float4 av = *(const float4*)(Ab + (size_t)row*K + kk + c4*4);
      As[c4*4+0][row]=av.x; As[c4*4+1][row]=av.y;
      As[c4*4+2][row]=av.z; As[c4*4+3][row]=av.w; }
    #pragma unroll
    for (int q = 0; q < 2; q++) {
      int idx = tid + q*256; int row = idx >> 3; int c4 = idx & 7;
      float4 bv = *(const float4*)(Bb + (size_t)row*K + kk + c4*4);
      Bs[c4*4+0][row]=bv.x; Bs[c4*4+1][row]=bv.y;
      Bs[c4*4+2][row]=bv.z; Bs[c4*4+3][row]=bv.w; }
    __syncthreads();
    #pragma unroll
    for (int k = 0; k < 32; k++) {
      float a0 = As[k][ty*2], a1 = As[k][ty*2+1];
      float4 b4 = *(const float4*)&Bs[k][tx*4];
      float bv[4] = {b4.x,b4.y,b4.z,b4.w};
      #pragma unroll
      for (int j=0;j<4;j++){ acc[0][j] += a0*bv[j]; acc[1][j] += a1*bv[j]; }
    }
    __syncthreads();
  }
  #pragma unroll
  for (int i = 0; i < 2; i++) {
    int m = mt*32 + ty*2 + i;
    float4 v; float* vv = (float*)&v;
    #pragma unroll
    for (int j = 0; j < 4; j++) vv[j] = acc[i][j] + bias[nt*64 + tx*4 + j];
    *(float4*)(&C[(size_t)m*N + nt*64 + tx*4]) = v;
  }
}

// ---------------- fused conv + delta, 4 rows/block (512 blocks) ----------------
__global__ __launch_bounds__(256) void k_convdelta(
    const float* __restrict__ P, const float* __restrict__ u,
    const float* __restrict__ cw, const float* __restrict__ cb,
    const float* __restrict__ Wg, const float* __restrict__ bg,
    const float* __restrict__ Wdt, const float* __restrict__ bdt,
    const float* __restrict__ Ap, bf16_t* __restrict__ oldbf,
    float* __restrict__ dA, float* __restrict__ coef){
  __shared__ __align__(16) float olds[4*KD_];
  __shared__ float dr[4][64];
  int tid = threadIdx.x;
  int m0 = blockIdx.x * 4;
  int b = m0 >> 7, l0 = m0 & 127;
  for (int e = tid; e < 4*CH_; e += 256) {
    int r = e / CH_, c = e - r*CH_;
    int l = l0 + r;
    float acc = cb[c];
    #pragma unroll
    for (int k = 0; k < 4; k++) {
      int t = l + k - 1;
      if (t >= 0 && t <= O_-2) {
        float s = (c < N_) ? P[((b<<7)+t)*N_ + c] : u[((b<<8)+t)*U_ + (c-N_)];
        acc += silu_f(s) * cw[c*4 + k];
      }
    }
    float v = silu_f(acc);
    olds[e] = v;
    oldbf[(size_t)(m0+r)*CH_ + c] = (bf16_t)v;
  }
  __syncthreads();
  {
    int d = tid & 63;
    int r = tid >> 6;
    const float* wrow = Wg + (size_t)d*KD_;
    const float* orow = olds + r*KD_;
    float s = 0.f;
    for (int k = 0; k < KD_; k++) s += orow[k] * wrow[k];
    dr[r][d] = s + bg[d];
  }
  __syncthreads();
  int n = tid;
  float wrow[64];
  #pragma unroll
  for (int d = 0; d < 64; d++) wrow[d] = Wdt[n*64 + d];
  float a0 = Ap[n];
  float a = -(a0 > 0.f ? a0 : expm1f(a0));
  float inva = 1.f / a;
  float bd = bdt[n];
  #pragma unroll
  for (int r = 0; r < 4; r++) {
    float s = bd;
    #pragma unroll
    for (int d = 0; d < 64; d++) s += dr[r][d] * wrow[d];
    float dd = softplus_f(s);
    float e  = expf(dd * a);
    size_t m = m0 + r;
    dA[m*N_ + n]   = e;
    coef[m*N_ + n] = (e - 1.f) * inva;
  }
}

// ================= fragment-order staging, BK=32 =================
#define STAGE_FR(GBASE, ROW0G, LDSARR)                                              \
  { _Pragma("unroll")                                                               \
    for (int q = 0; q < 2; q++) {                                                   \
      int g = wave*2 + q;                                                           \
      const bf16_t* gp = (GBASE) + (size_t)((ROW0G) + g*16 + lm)*KD_ + kk + lq*8;   \
      __builtin_amdgcn_global_load_lds(AS1(gp), AS3(&(LDSARR)[g*512]), 16, 0, 0);   \
    } }

// ================= fragment-order staging, BK=96 (3 col-blocks of 32) =================
#define STAGE_FR96(GBASE, ROW0G, LDSARR)                                                 \
  { _Pragma("unroll")                                                                    \
    for (int c = 0; c < 3; c++) {                                                        \
      _Pragma("unroll")                                                                  \
      for (int q = 0; q < 2; q++) {                                                      \
        int g = wave*2 + q;                                                              \
        const bf16_t* gp = (GBASE) + (size_t)((ROW0G) + g*16 + lm)*KD_ + kk + c*32 + lq*8;\
        __builtin_amdgcn_global_load_lds(AS1(gp), AS3(&(LDSARR)[c*4096 + g*512]), 16, 0, 0);\
      } } }

// ---------------- B-path MFMA (BK=96) ----------------
__global__ __launch_bounds__(256, 2) void k_bmfma(
    const bf16_t* __restrict__ oldbf, const bf16_t* __restrict__ Wgbf,
    const float* __restrict__ bg, const float* __restrict__ u,
    const float* __restrict__ coef, float* __restrict__ wbuf){
  __shared__ __align__(16) bf16_t Asb[3*4096];
  __shared__ __align__(16) bf16_t Bsb[3*4096];
  int tid = threadIdx.x;
  int wave = tid >> 6, lane = tid & 63;
  int wm = wave & 1, wn = wave >> 1;
  int mt = blockIdx.y, nt = blockIdx.x;
  int m0 = mt*128, ncol0 = nt*128;
  int lm = lane & 15, lq = lane >> 4;

  f32x4 acc[4][4];
  #pragma unroll
  for (int i=0;i<4;i++)
    #pragma unroll
    for (int j=0;j<4;j++){ acc[i][j][0]=0.f;acc[i][j][1]=0.f;acc[i][j][2]=0.f;acc[i][j][3]=0.f; }

  for (int kk = 0; kk < KD_; kk += 96) {
    STAGE_FR96(oldbf, m0, Asb);
    STAGE_FR96(Wgbf, DEL_ + ncol0, Bsb);
    __syncthreads();
    for (int c = 0; c < 3; c++) {
      bf16x8 af[4], bff[4];
      #pragma unroll
      for (int i=0;i<4;i++) af[i]  = *(const bf16x8*)&Asb[c*4096 + (wm*4 + i)*512 + lane*8];
      #pragma unroll
      for (int j=0;j<4;j++) bff[j] = *(const bf16x8*)&Bsb[c*4096 + (wn*4 + j)*512 + lane*8];
      #pragma unroll
      for (int i=0;i<4;i++)
        #pragma unroll
        for (int j=0;j<4;j++)
          acc[i][j] = __builtin_amdgcn_mfma_f32_16x16x32_bf16(af[i], bff[j], acc[i][j], 0,0,0);
    }
    __syncthreads();
  }

  float bgv[4];
  #pragma unroll
  for (int j=0;j<4;j++) bgv[j] = bg[DEL_ + ncol0 + wn*64 + j*16 + lm];
  float p[2][4][4];
  #pragma unroll
  for (int a=0;a<2;a++)
    #pragma unroll
    for (int i=0;i<4;i++)
      #pragma unroll
      for (int r=0;r<4;r++) p[a][i][r]=0.f;
  #pragma unroll
  for (int i=0;i<4;i++){
    #pragma unroll
    for (int r=0;r<4;r++){
      int m = m0 + wm*64 + i*16 + lq*4 + r;
      int b = m >> 7, l = m & 127;
      const float* urow = u + ((size_t)(b<<8) + 127 + l)*U_;
      #pragma unroll
      for (int j=0;j<4;j++){
        float uu = urow[(j&1)*16 + lm];
        p[j>>1][i][r] += (acc[i][j][r] + bgv[j]) * uu;
      }
    }
  }
  #pragma unroll
  for (int mk = 1; mk < 16; mk <<= 1){
    #pragma unroll
    for (int a=0;a<2;a++)
      #pragma unroll
      for (int i=0;i<4;i++)
        #pragma unroll
        for (int r=0;r<4;r++) p[a][i][r] += __shfl_xor(p[a][i][r], mk);
  }
  if (lm == 0){
    #pragma unroll
    for (int nl=0;nl<2;nl++){
      int n = ((ncol0 + wn*64 + nl*32) >> 5);
      #pragma unroll
      for (int i=0;i<4;i++)
        #pragma unroll
        for (int r=0;r<4;r++){
          int m = m0 + wm*64 + i*16 + lq*4 + r;
          wbuf[(size_t)m*N_ + n] = coef[(size_t)m*N_ + n] * p[nl][i][r];
        }
    }
  }
}

// ---------------- sequential scan (batched loads) ----------------
__global__ void k_scan(const float* __restrict__ P, const float* __restrict__ dA,
                       const float* __restrict__ w, float* __restrict__ zall){
  int blk = blockIdx.x;             // 64
  int b = blk >> 2;
  int n = (blk & 3)*64 + threadIdx.x;
  float z = P[(size_t)((b<<7) + 127)*N_ + n];
  for (int l0 = 0; l0 < L_; l0 += 16) {
    float da[16], ww[16];
    #pragma unroll
    for (int t = 0; t < 16; t++) {
      size_t idx = (size_t)((b<<7) + l0 + t)*N_ + n;
      da[t] = dA[idx]; ww[t] = w[idx];
    }
    #pragma unroll
    for (int t = 0; t < 16; t++) {
      size_t idx = (size_t)((b<<7) + l0 + t)*N_ + n;
      z = z * da[t] + ww[t];
      zall[idx] = z;
    }
  }
}

// ---------------- C-path MFMA v2: yacc in LDS, BK=32, 3 blocks/CU ----------------
// ylds is s-major [64][132] (+4 pad -> 2-way-free banks). Per n-tile the two
// wn-halves RMW it in two phases; registers hold only the MFMA acc.
__global__ __launch_bounds__(256) void k_cmfma(
    const bf16_t* __restrict__ oldbf, const bf16_t* __restrict__ Wgbf,
    const float* __restrict__ bg, const float* __restrict__ zall,
    float* __restrict__ ypart){
  __shared__ __align__(16) bf16_t Asb[128*32];   // 8 KB
  __shared__ __align__(16) bf16_t Bsb[128*32];   // 8 KB
  __shared__ __align__(16) float ylds[64][132];  // 33.8 KB
  int tid = threadIdx.x;
  int wave = tid >> 6, lane = tid & 63;
  int wm = wave & 1, wn = wave >> 1;
  int mt = blockIdx.y, grp = blockIdx.x;   // 32 groups of 4 n-tiles
  int m0 = mt*128;
  int lm = lane & 15, lq = lane >> 4;

  for (int e = tid; e < 64*132; e += 256) ((float*)ylds)[e] = 0.f;
  __syncthreads();

  for (int it = 0; it < 4; it++) {
    int ncol0 = (grp*4 + it)*128;
    f32x4 acc[4][4];
    #pragma unroll
    for (int i=0;i<4;i++)
      #pragma unroll
      for (int j=0;j<4;j++){ acc[i][j][0]=0.f;acc[i][j][1]=0.f;acc[i][j][2]=0.f;acc[i][j][3]=0.f; }

    for (int kk = 0; kk < KD_; kk += 32) {
      STAGE_FR(oldbf, m0, Asb);
      STAGE_FR(Wgbf, CM_BASE + ncol0, Bsb);
      __syncthreads();
      bf16x8 af[4], bff[4];
      #pragma unroll
      for (int i=0;i<4;i++) af[i]  = *(const bf16x8*)&Asb[(wm*4 + i)*512 + lane*8];
      #pragma unroll
      for (int j=0;j<4;j++) bff[j] = *(const bf16x8*)&Bsb[(wn*4 + j)*512 + lane*8];
      #pragma unroll
      for (int i=0;i<4;i++)
        #pragma unroll
        for (int j=0;j<4;j++)
          acc[i][j] = __builtin_amdgcn_mfma_f32_16x16x32_bf16(af[i], bff[j], acc[i][j], 0,0,0);
      __syncthreads();
    }

    int n = (ncol0 >> 6) + wn;
    float bgv[4];
    #pragma unroll
    for (int j=0;j<4;j++) bgv[j] = bg[CM_BASE + ncol0 + wn*64 + j*16 + lm];

    #pragma unroll
    for (int phase = 0; phase < 2; phase++) {
      if ((phase == 0) == (wn == 1)) {
        #pragma unroll
        for (int i=0;i<4;i++){
          int mb = wm*64 + i*16 + lq*4;
          float z0 = zall[(size_t)(m0+mb+0)*N_ + n];
          float z1 = zall[(size_t)(m0+mb+1)*N_ + n];
          float z2 = zall[(size_t)(m0+mb+2)*N_ + n];
          float z3 = zall[(size_t)(m0+mb+3)*N_ + n];
          #pragma unroll
          for (int j=0;j<4;j++){
            int s = j*16 + lm;
            float4* p4 = (float4*)&ylds[s][mb];
            float4 v = *p4;
            v.x += (acc[i][j][0] + bgv[j]) * z0;
            v.y += (acc[i][j][1] + bgv[j]) * z1;
            v.z += (acc[i][j][2] + bgv[j]) * z2;
            v.w += (acc[i][j][3] + bgv[j]) * z3;
            *p4 = v;
          }
        }
      }
      __syncthreads();
    }
  }

  // drain ylds -> ypart slice (coalesced 16B stores)
  float* dst = ypart + (size_t)grp*(M_*S_) + (size_t)m0*S_;
  #pragma unroll
  for (int q = 0; q < 8; q++){
    int e = q*1024 + tid*4;       // e = ml*64 + s, s multiple of 4
    int ml = e >> 6, s = e & 63;
    float4 v;
    v.x = ylds[s+0][ml]; v.y = ylds[s+1][ml];
    v.z = ylds[s+2][ml]; v.w = ylds[s+3][ml];
    *(float4*)&dst[e] = v;
  }
}

// ---------------- finalize: sum slices, write ys (L,B,S), fused loss ----------------
__global__ void k_finalize(const float* __restrict__ ypart, const float* __restrict__ x,
                           float* __restrict__ out, float* __restrict__ lossacc){
  __shared__ float red[256];
  int tid = threadIdx.x;
  float ls = 0.f;
  #pragma unroll
  for (int q = 0; q < 2; q++) {
    int e = blockIdx.x*512 + q*256 + tid;
    int m = e >> 6, s = e & 63;
    int b = m >> 7, l = m & 127;
    float yv = 0.f;
    #pragma unroll 8
    for (int g = 0; g < NSLICE; g++) yv += ypart[(size_t)g*(M_*S_) + e];
    out[1 + (size_t)((l<<4) + b)*S_ + s] = yv;
    float xv = x[((size_t)(b<<8) + 128 + l)*S_ + s];
    float d = yv - xv;
    ls += d*d;
  }
  red[tid] = ls; __syncthreads();
  for (int st = 128; st > 0; st >>= 1) {
    if (tid < st) red[tid] += red[tid+st];
    __syncthreads();
  }
  if (tid == 0) {
    atomicAdd(&lossacc[0], red[0]);
    __threadfence();
    unsigned old = atomicAdd((unsigned*)&lossacc[1], 1u);
    if (old == 255u) {
      float tot = atomicAdd(&lossacc[0], 0.f);   // atomic read (bypass L1)
      out[0] = tot * (1.f / (float)(B_*S_*L_));
    }
  }
}

extern "C" void kernel_launch(void* const* d_in, const int* in_sizes, int n_in,
                              void* d_out, int out_size, void* d_ws, size_t ws_size,
                              hipStream_t stream) {
  const float* x   = (const float*)d_in[0];
  const float* u   = (const float*)d_in[1];
  const float* Ap  = (const float*)d_in[2];
  const float* W0  = (const float*)d_in[3];
  const float* b0  = (const float*)d_in[4];
  const float* W1  = (const float*)d_in[5];
  const float* b1  = (const float*)d_in[6];
  const float* cw  = (const float*)d_in[7];
  const float* cb  = (const float*)d_in[8];
  const float* Wg  = (const float*)d_in[9];
  const float* bg  = (const float*)d_in[10];
  const float* Wdt = (const float*)d_in[11];
  const float* bdt = (const float*)d_in[12];
  float* out = (float*)d_out;

  // Layout: persistent buffers first; region R of fp32 temps (dead before
  // k_cmfma) is overlaid by ypart (32 slices = 16 MB).
  float* ws    = (float*)d_ws;
  float* zall  = ws;                       // 524288
  float* lossa = zall + 524288;            // 512 (acc, counter)
  bf16_t* oldbf = (bf16_t*)(lossa + 512);  // 294912 f32 slots
  bf16_t* Wgbf  = (bf16_t*)(lossa + 512 + 294912);  // 3548160 f32 slots
  float* R     = lossa + 512 + 294912 + 3548160;
  float* Hh    = R;                        // 1048576
  float* Pp    = Hh   + 1048576;           // 524288
  float* dA    = Pp   + 524288;            // 524288
  float* coef  = dA   + 524288;            // 524288
  float* wbuf  = coef + 524288;            // 524288
  float* ypart = R;                        // 32*131072 = 4194304, overlays R

  k_prep<<<CVT_BLOCKS, 256, 0, stream>>>(Wg, Wgbf, lossa);
  k_mlp1<<<dim3(HID_/64, M_/64), 256, 0, stream>>>(x, W0, b0, Hh);
  k_gemm_tn_s<<<dim3(N_/64, M_/32), 256, 0, stream>>>(Hh, W1, b1, Pp, M_, N_, HID_);
  k_convdelta<<<M_/4, 256, 0, stream>>>(Pp, u, cw, cb, Wg, bg, Wdt, bdt, Ap,
                                        oldbf, dA, coef);
  k_bmfma<<<dim3(64, 16), 256, 0, stream>>>(oldbf, Wgbf, bg, u, coef, wbuf);
  k_scan<<<64, 64, 0, stream>>>(Pp, dA, wbuf, zall);
  k_cmfma<<<dim3(32, 16), 256, 0, stream>>>(oldbf, Wgbf, bg, zall, ypart);
  k_finalize<<<256, 256, 0, stream>>>(ypart, x, out, lossa);
}

// Round 13
// 240.358 us; speedup vs baseline: 1.1567x; 1.1567x over previous
//
#include <hip/hip_runtime.h>
#include <math.h>

#define B_   16
#define L_   128
#define O_   128
#define N_   256
#define S_   64
#define U_   32
#define DEL_ 64
#define HID_ 512
#define CH_  288          // N_+U_
#define M_   2048         // B_*L_
#define KD_  288          // GEMM K for the Wg projections
#define CM_BASE (DEL_ + N_*U_)   // 8256
#define NSLICE 32

typedef __bf16 bf16_t;
typedef bf16_t bf16x8 __attribute__((ext_vector_type(8)));
typedef float  f32x4  __attribute__((ext_vector_type(4)));

#define AS1(p) ((const __attribute__((address_space(1))) void*)(unsigned long long)(const void*)(p))
#define AS3(p) ((__attribute__((address_space(3))) void*)(unsigned int)(unsigned long long)(const void*)(p))

__device__ __forceinline__ float silu_f(float x){ return x / (1.f + expf(-x)); }
__device__ __forceinline__ float softplus_f(float x){
  return fmaxf(x, 0.f) + log1pf(expf(-fabsf(x)));
}

// ---------------- prep: Wg->bf16 convert + zero loss acc ----------------
#define CVT_BLOCKS 3465   // ceil(887040/256)
__global__ void k_prep(const float* __restrict__ Wg, bf16_t* __restrict__ Wgbf,
                       float* __restrict__ lossa){
  if (blockIdx.x == 0 && threadIdx.x < 2) lossa[threadIdx.x] = 0.f;
  int i = blockIdx.x*256 + threadIdx.x;
  if (i >= 887040) return;          // 7096320/8
  float4 a = ((const float4*)Wg)[2*i];
  float4 b = ((const float4*)Wg)[2*i+1];
  bf16x8 o;
  o[0]=(bf16_t)a.x; o[1]=(bf16_t)a.y; o[2]=(bf16_t)a.z; o[3]=(bf16_t)a.w;
  o[4]=(bf16_t)b.x; o[5]=(bf16_t)b.y; o[6]=(bf16_t)b.z; o[7]=(bf16_t)b.w;
  ((bf16x8*)Wgbf)[i] = o;
}

// ---------------- mlp1: H = relu(x[:, t<128] @ W0.T + b0), direct-x A load ----------------
__global__ __launch_bounds__(256) void k_mlp1(
    const float* __restrict__ x, const float* __restrict__ W0,
    const float* __restrict__ b0, float* __restrict__ Hh){
  __shared__ __align__(16) float As[32][68];
  __shared__ __align__(16) float Bs[32][68];
  int tid = threadIdx.x, tx = tid & 15, ty = tid >> 4;
  int nt = blockIdx.x, mt = blockIdx.y;
  const float* Bb = W0 + (size_t)nt*64*S_;
  float acc[4][4] = {};
  for (int kk = 0; kk < S_; kk += 32) {
    #pragma unroll
    for (int q = 0; q < 2; q++) {
      int idx = tid + q*256; int row = idx >> 3; int c4 = idx & 7;
      int grow = mt*64 + row;
      const float* ap = x + (size_t)((((grow>>7)<<8) + (grow&127))<<6) + kk + c4*4;
      float4 av = *(const float4*)ap;
      float4 bv = *(const float4*)(Bb + (size_t)row*S_ + kk + c4*4);
      As[c4*4+0][row]=av.x; As[c4*4+1][row]=av.y;
      As[c4*4+2][row]=av.z; As[c4*4+3][row]=av.w;
      Bs[c4*4+0][row]=bv.x; Bs[c4*4+1][row]=bv.y;
      Bs[c4*4+2][row]=bv.z; Bs[c4*4+3][row]=bv.w;
    }
    __syncthreads();
    #pragma unroll
    for (int k = 0; k < 32; k++) {
      float4 a4 = *(const float4*)&As[k][ty*4];
      float4 b4 = *(const float4*)&Bs[k][tx*4];
      float av[4] = {a4.x,a4.y,a4.z,a4.w};
      float bv[4] = {b4.x,b4.y,b4.z,b4.w};
      #pragma unroll
      for (int i=0;i<4;i++)
        #pragma unroll
        for (int j=0;j<4;j++) acc[i][j] += av[i]*bv[j];
    }
    __syncthreads();
  }
  #pragma unroll
  for (int i = 0; i < 4; i++) {
    int m = mt*64 + ty*4 + i;
    float4 v; float* vv = (float*)&v;
    #pragma unroll
    for (int j = 0; j < 4; j++)
      vv[j] = fmaxf(acc[i][j] + b0[nt*64 + tx*4 + j], 0.f);
    *(float4*)(&Hh[(size_t)m*HID_ + nt*64 + tx*4]) = v;
  }
}

// ---------------- fp32 TN GEMM, 32x64 tile (mlp2: 256 blocks) ----------------
__global__ __launch_bounds__(256) void k_gemm_tn_s(
    const float* __restrict__ A, const float* __restrict__ B,
    const float* __restrict__ bias, float* __restrict__ C,
    int M, int N, int K){
  __shared__ __align__(16) float As[32][36];
  __shared__ __align__(16) float Bs[32][68];
  int tid = threadIdx.x, tx = tid & 15, ty = tid >> 4;
  int nt = blockIdx.x, mt = blockIdx.y;
  const float* Ab = A + (size_t)mt*32*K;
  const float* Bb = B + (size_t)nt*64*K;
  float acc[2][4] = {};
  for (int kk = 0; kk < K; kk += 32) {
    { int row = tid >> 3, c4 = tid & 7;
      float4 av = *(const float4*)(Ab + (size_t)row*K + kk + c4*4);
      As[c4*4+0][row]=av.x; As[c4*4+1][row]=av.y;
      As[c4*4+2][row]=av.z; As[c4*4+3][row]=av.w; }
    #pragma unroll
    for (int q = 0; q < 2; q++) {
      int idx = tid + q*256; int row = idx >> 3; int c4 = idx & 7;
      float4 bv = *(const float4*)(Bb + (size_t)row*K + kk + c4*4);
      Bs[c4*4+0][row]=bv.x; Bs[c4*4+1][row]=bv.y;
      Bs[c4*4+2][row]=bv.z; Bs[c4*4+3][row]=bv.w; }
    __syncthreads();
    #pragma unroll
    for (int k = 0; k < 32; k++) {
      float a0 = As[k][ty*2], a1 = As[k][ty*2+1];
      float4 b4 = *(const float4*)&Bs[k][tx*4];
      float bv[4] = {b4.x,b4.y,b4.z,b4.w};
      #pragma unroll
      for (int j=0;j<4;j++){ acc[0][j] += a0*bv[j]; acc[1][j] += a1*bv[j]; }
    }
    __syncthreads();
  }
  #pragma unroll
  for (int i = 0; i < 2; i++) {
    int m = mt*32 + ty*2 + i;
    float4 v; float* vv = (float*)&v;
    #pragma unroll
    for (int j = 0; j < 4; j++) vv[j] = acc[i][j] + bias[nt*64 + tx*4 + j];
    *(float4*)(&C[(size_t)m*N + nt*64 + tx*4]) = v;
  }
}

// ---------------- fused conv + delta, 4 rows/block (512 blocks) ----------------
__global__ __launch_bounds__(256) void k_convdelta(
    const float* __restrict__ P, const float* __restrict__ u,
    const float* __restrict__ cw, const float* __restrict__ cb,
    const float* __restrict__ Wg, const float* __restrict__ bg,
    const float* __restrict__ Wdt, const float* __restrict__ bdt,
    const float* __restrict__ Ap, bf16_t* __restrict__ oldbf,
    float* __restrict__ dA, float* __restrict__ coef){
  __shared__ __align__(16) float olds[4*KD_];
  __shared__ float dr[4][64];
  int tid = threadIdx.x;
  int m0 = blockIdx.x * 4;
  int b = m0 >> 7, l0 = m0 & 127;
  for (int e = tid; e < 4*CH_; e += 256) {
    int r = e / CH_, c = e - r*CH_;
    int l = l0 + r;
    float acc = cb[c];
    #pragma unroll
    for (int k = 0; k < 4; k++) {
      int t = l + k - 1;
      if (t >= 0 && t <= O_-2) {
        float s = (c < N_) ? P[((b<<7)+t)*N_ + c] : u[((b<<8)+t)*U_ + (c-N_)];
        acc += silu_f(s) * cw[c*4 + k];
      }
    }
    float v = silu_f(acc);
    olds[e] = v;
    oldbf[(size_t)(m0+r)*CH_ + c] = (bf16_t)v;
  }
  __syncthreads();
  {
    int d = tid & 63;
    int r = tid >> 6;
    const float* wrow = Wg + (size_t)d*KD_;
    const float* orow = olds + r*KD_;
    float s = 0.f;
    for (int k = 0; k < KD_; k++) s += orow[k] * wrow[k];
    dr[r][d] = s + bg[d];
  }
  __syncthreads();
  int n = tid;
  float wrow[64];
  #pragma unroll
  for (int d = 0; d < 64; d++) wrow[d] = Wdt[n*64 + d];
  float a0 = Ap[n];
  float a = -(a0 > 0.f ? a0 : expm1f(a0));
  float inva = 1.f / a;
  float bd = bdt[n];
  #pragma unroll
  for (int r = 0; r < 4; r++) {
    float s = bd;
    #pragma unroll
    for (int d = 0; d < 64; d++) s += dr[r][d] * wrow[d];
    float dd = softplus_f(s);
    float e  = expf(dd * a);
    size_t m = m0 + r;
    dA[m*N_ + n]   = e;
    coef[m*N_ + n] = (e - 1.f) * inva;
  }
}

// ================= fragment-order staging, BK=96 (3 col-blocks of 32) =================
#define STAGE_FR96(GBASE, ROW0G, LDSARR)                                                 \
  { _Pragma("unroll")                                                                    \
    for (int c = 0; c < 3; c++) {                                                        \
      _Pragma("unroll")                                                                  \
      for (int q = 0; q < 2; q++) {                                                      \
        int g = wave*2 + q;                                                              \
        const bf16_t* gp = (GBASE) + (size_t)((ROW0G) + g*16 + lm)*KD_ + kk + c*32 + lq*8;\
        __builtin_amdgcn_global_load_lds(AS1(gp), AS3(&(LDSARR)[c*4096 + g*512]), 16, 0, 0);\
      } } }

// ---------------- B-path MFMA (BK=96) + fused Kogge-Stone scan -> zall ----------------
// Block (nt, mt): batch b=mt, n-cols nt*4..nt*4+3, all 128 l. After the GEMM
// epilogue, w goes to LDS (overlaying dead staging), dA columns are preloaded,
// and each wave runs a 64-lane parallel scan (2 l/lane) for its n-column.
__global__ __launch_bounds__(256, 2) void k_bmfma(
    const bf16_t* __restrict__ oldbf, const bf16_t* __restrict__ Wgbf,
    const float* __restrict__ bg, const float* __restrict__ u,
    const float* __restrict__ coef, const float* __restrict__ dAg,
    const float* __restrict__ Pg, float* __restrict__ zall){
  __shared__ union {
    struct { __align__(16) bf16_t A[3*4096]; __align__(16) bf16_t B[3*4096]; } st;
    struct { float wl[128][4]; float dal[128][4]; } sc;   // 4 KB, used post-GEMM
  } sm;
  int tid = threadIdx.x;
  int wave = tid >> 6, lane = tid & 63;
  int wm = wave & 1, wn = wave >> 1;
  int mt = blockIdx.y, nt = blockIdx.x;
  int m0 = mt*128, ncol0 = nt*128;
  int lm = lane & 15, lq = lane >> 4;

  f32x4 acc[4][4];
  #pragma unroll
  for (int i=0;i<4;i++)
    #pragma unroll
    for (int j=0;j<4;j++){ acc[i][j][0]=0.f;acc[i][j][1]=0.f;acc[i][j][2]=0.f;acc[i][j][3]=0.f; }

  for (int kk = 0; kk < KD_; kk += 96) {
    STAGE_FR96(oldbf, m0, sm.st.A);
    STAGE_FR96(Wgbf, DEL_ + ncol0, sm.st.B);
    __syncthreads();
    for (int c = 0; c < 3; c++) {
      bf16x8 af[4], bff[4];
      #pragma unroll
      for (int i=0;i<4;i++) af[i]  = *(const bf16x8*)&sm.st.A[c*4096 + (wm*4 + i)*512 + lane*8];
      #pragma unroll
      for (int j=0;j<4;j++) bff[j] = *(const bf16x8*)&sm.st.B[c*4096 + (wn*4 + j)*512 + lane*8];
      #pragma unroll
      for (int i=0;i<4;i++)
        #pragma unroll
        for (int j=0;j<4;j++)
          acc[i][j] = __builtin_amdgcn_mfma_f32_16x16x32_bf16(af[i], bff[j], acc[i][j], 0,0,0);
    }
    __syncthreads();
  }

  // staging LDS is dead now: preload dA columns for the fused scan
  for (int e = tid; e < 512; e += 256)
    sm.sc.dal[e>>2][e&3] = dAg[(size_t)(m0 + (e>>2))*N_ + nt*4 + (e&3)];

  float bgv[4];
  #pragma unroll
  for (int j=0;j<4;j++) bgv[j] = bg[DEL_ + ncol0 + wn*64 + j*16 + lm];
  float p[2][4][4];
  #pragma unroll
  for (int a=0;a<2;a++)
    #pragma unroll
    for (int i=0;i<4;i++)
      #pragma unroll
      for (int r=0;r<4;r++) p[a][i][r]=0.f;
  #pragma unroll
  for (int i=0;i<4;i++){
    #pragma unroll
    for (int r=0;r<4;r++){
      int m = m0 + wm*64 + i*16 + lq*4 + r;
      int b = m >> 7, l = m & 127;
      const float* urow = u + ((size_t)(b<<8) + 127 + l)*U_;
      #pragma unroll
      for (int j=0;j<4;j++){
        float uu = urow[(j&1)*16 + lm];
        p[j>>1][i][r] += (acc[i][j][r] + bgv[j]) * uu;
      }
    }
  }
  #pragma unroll
  for (int mk = 1; mk < 16; mk <<= 1){
    #pragma unroll
    for (int a=0;a<2;a++)
      #pragma unroll
      for (int i=0;i<4;i++)
        #pragma unroll
        for (int r=0;r<4;r++) p[a][i][r] += __shfl_xor(p[a][i][r], mk);
  }
  if (lm == 0){
    #pragma unroll
    for (int nl=0;nl<2;nl++){
      int n = ((ncol0 + wn*64 + nl*32) >> 5);
      int nc = wn*2 + nl;
      #pragma unroll
      for (int i=0;i<4;i++)
        #pragma unroll
        for (int r=0;r<4;r++){
          int l = wm*64 + i*16 + lq*4 + r;
          sm.sc.wl[l][nc] = coef[(size_t)(m0+l)*N_ + n] * p[nl][i][r];
        }
    }
  }
  __syncthreads();

  // fused scan: wave handles n-column nc=wave; 2 l per lane, Kogge-Stone
  {
    int nc = wave;
    int n = nt*4 + nc;
    float z0 = Pg[(size_t)(m0 + 127)*N_ + n];
    int l0 = lane*2;
    float a0 = sm.sc.dal[l0][nc],   w0 = sm.sc.wl[l0][nc];
    float a1 = sm.sc.dal[l0+1][nc], w1 = sm.sc.wl[l0+1][nc];
    float A = a0*a1, Bv = w0*a1 + w1;    // pair-composed affine (z -> z*A + Bv)
    #pragma unroll
    for (int d = 1; d < 64; d <<= 1){
      float Ap = __shfl_up(A, d);
      float Bp = __shfl_up(Bv, d);
      if (lane >= d){ Bv = Bp*A + Bv; A = Ap*A; }
    }
    float Ae = __shfl_up(A, 1);
    float Be = __shfl_up(Bv, 1);
    if (lane == 0){ Ae = 1.f; Be = 0.f; }
    float zp = z0*Ae + Be;               // z after previous pair
    float za = zp*a0 + w0;               // z at l0
    float zb = za*a1 + w1;               // z at l0+1
    zall[(size_t)(m0 + l0)*N_ + n]     = za;
    zall[(size_t)(m0 + l0 + 1)*N_ + n] = zb;
  }
}

// ---------------- C-path MFMA (BK=96): 4 n-tiles/block, per-block y slice ----------------
__global__ __launch_bounds__(256, 2) void k_cmfma(
    const bf16_t* __restrict__ oldbf, const bf16_t* __restrict__ Wgbf,
    const float* __restrict__ bg, const float* __restrict__ zall,
    float* __restrict__ ypart){
  __shared__ union {
    struct { bf16_t A[3*4096]; bf16_t B[3*4096]; } st;   // 48 KB staging
    float ylds[128][64];                                  // 32 KB (after staging dead)
  } sm;
  int tid = threadIdx.x;
  int wave = tid >> 6, lane = tid & 63;
  int wm = wave & 1, wn = wave >> 1;
  int mt = blockIdx.y, grp = blockIdx.x;   // 32 groups of 4 n-tiles
  int m0 = mt*128;
  int lm = lane & 15, lq = lane >> 4;

  f32x4 yacc[4][4];
  #pragma unroll
  for (int i=0;i<4;i++)
    #pragma unroll
    for (int j=0;j<4;j++){ yacc[i][j][0]=0.f;yacc[i][j][1]=0.f;yacc[i][j][2]=0.f;yacc[i][j][3]=0.f; }

  for (int it = 0; it < 4; it++) {
    int ncol0 = (grp*4 + it)*128;
    f32x4 acc[4][4];
    #pragma unroll
    for (int i=0;i<4;i++)
      #pragma unroll
      for (int j=0;j<4;j++){ acc[i][j][0]=0.f;acc[i][j][1]=0.f;acc[i][j][2]=0.f;acc[i][j][3]=0.f; }

    for (int kk = 0; kk < KD_; kk += 96) {
      STAGE_FR96(oldbf, m0, sm.st.A);
      STAGE_FR96(Wgbf, CM_BASE + ncol0, sm.st.B);
      __syncthreads();
      for (int c = 0; c < 3; c++) {
        bf16x8 af[4], bff[4];
        #pragma unroll
        for (int i=0;i<4;i++) af[i]  = *(const bf16x8*)&sm.st.A[c*4096 + (wm*4 + i)*512 + lane*8];
        #pragma unroll
        for (int j=0;j<4;j++) bff[j] = *(const bf16x8*)&sm.st.B[c*4096 + (wn*4 + j)*512 + lane*8];
        #pragma unroll
        for (int i=0;i<4;i++)
          #pragma unroll
          for (int j=0;j<4;j++)
            acc[i][j] = __builtin_amdgcn_mfma_f32_16x16x32_bf16(af[i], bff[j], acc[i][j], 0,0,0);
      }
      __syncthreads();
    }

    int n = (ncol0 >> 6) + wn;
    float bgv[4];
    #pragma unroll
    for (int j=0;j<4;j++) bgv[j] = bg[CM_BASE + ncol0 + wn*64 + j*16 + lm];
    #pragma unroll
    for (int i=0;i<4;i++){
      #pragma unroll
      for (int r=0;r<4;r++){
        int m = m0 + wm*64 + i*16 + lq*4 + r;
        float zv = zall[(size_t)m*N_ + n];
        #pragma unroll
        for (int j=0;j<4;j++)
          yacc[i][j][r] += (acc[i][j][r] + bgv[j]) * zv;
      }
    }
  }

  __syncthreads();
  if (wn == 1){
    #pragma unroll
    for (int i=0;i<4;i++)
      #pragma unroll
      for (int j=0;j<4;j++)
        #pragma unroll
        for (int r=0;r<4;r++){
          int ml = wm*64 + i*16 + lq*4 + r;
          sm.ylds[ml][j*16 + lm] = yacc[i][j][r];
        }
  }
  __syncthreads();
  if (wn == 0){
    float* dst = ypart + (size_t)grp*(M_*S_);
    #pragma unroll
    for (int i=0;i<4;i++)
      #pragma unroll
      for (int j=0;j<4;j++)
        #pragma unroll
        for (int r=0;r<4;r++){
          int ml = wm*64 + i*16 + lq*4 + r;
          int s = j*16 + lm;
          dst[(size_t)(m0+ml)*S_ + s] = yacc[i][j][r] + sm.ylds[ml][s];
        }
  }
}

// ---------------- finalize: sum slices, write ys (L,B,S), fused loss ----------------
__global__ void k_finalize(const float* __restrict__ ypart, const float* __restrict__ x,
                           float* __restrict__ out, float* __restrict__ lossacc){
  __shared__ float red[256];
  int tid = threadIdx.x;
  float ls = 0.f;
  #pragma unroll
  for (int q = 0; q < 2; q++) {
    int e = blockIdx.x*512 + q*256 + tid;
    int m = e >> 6, s = e & 63;
    int b = m >> 7, l = m & 127;
    float yv = 0.f;
    #pragma unroll 8
    for (int g = 0; g < NSLICE; g++) yv += ypart[(size_t)g*(M_*S_) + e];
    out[1 + (size_t)((l<<4) + b)*S_ + s] = yv;
    float xv = x[((size_t)(b<<8) + 128 + l)*S_ + s];
    float d = yv - xv;
    ls += d*d;
  }
  red[tid] = ls; __syncthreads();
  for (int st = 128; st > 0; st >>= 1) {
    if (tid < st) red[tid] += red[tid+st];
    __syncthreads();
  }
  if (tid == 0) {
    atomicAdd(&lossacc[0], red[0]);
    __threadfence();
    unsigned old = atomicAdd((unsigned*)&lossacc[1], 1u);
    if (old == 255u) {
      float tot = atomicAdd(&lossacc[0], 0.f);   // atomic read (bypass L1)
      out[0] = tot * (1.f / (float)(B_*S_*L_));
    }
  }
}

extern "C" void kernel_launch(void* const* d_in, const int* in_sizes, int n_in,
                              void* d_out, int out_size, void* d_ws, size_t ws_size,
                              hipStream_t stream) {
  const float* x   = (const float*)d_in[0];
  const float* u   = (const float*)d_in[1];
  const float* Ap  = (const float*)d_in[2];
  const float* W0  = (const float*)d_in[3];
  const float* b0  = (const float*)d_in[4];
  const float* W1  = (const float*)d_in[5];
  const float* b1  = (const float*)d_in[6];
  const float* cw  = (const float*)d_in[7];
  const float* cb  = (const float*)d_in[8];
  const float* Wg  = (const float*)d_in[9];
  const float* bg  = (const float*)d_in[10];
  const float* Wdt = (const float*)d_in[11];
  const float* bdt = (const float*)d_in[12];
  float* out = (float*)d_out;

  // Layout: persistent buffers first; region R of fp32 temps (all dead before
  // k_cmfma) is overlaid by ypart (32 slices = 16 MB).
  float* ws    = (float*)d_ws;
  float* zall  = ws;                       // 524288
  float* lossa = zall + 524288;            // 512 (acc, counter)
  bf16_t* oldbf = (bf16_t*)(lossa + 512);  // 294912 f32 slots
  bf16_t* Wgbf  = (bf16_t*)(lossa + 512 + 294912);  // 3548160 f32 slots
  float* R     = lossa + 512 + 294912 + 3548160;
  float* Hh    = R;                        // 1048576
  float* Pp    = Hh   + 1048576;           // 524288
  float* dA    = Pp   + 524288;            // 524288
  float* coef  = dA   + 524288;            // 524288
  float* ypart = R;                        // 32*131072 = 4194304, overlays R

  k_prep<<<CVT_BLOCKS, 256, 0, stream>>>(Wg, Wgbf, lossa);
  k_mlp1<<<dim3(HID_/64, M_/64), 256, 0, stream>>>(x, W0, b0, Hh);
  k_gemm_tn_s<<<dim3(N_/64, M_/32), 256, 0, stream>>>(Hh, W1, b1, Pp, M_, N_, HID_);
  k_convdelta<<<M_/4, 256, 0, stream>>>(Pp, u, cw, cb, Wg, bg, Wdt, bdt, Ap,
                                        oldbf, dA, coef);
  k_bmfma<<<dim3(64, 16), 256, 0, stream>>>(oldbf, Wgbf, bg, u, coef, dA, Pp, zall);
  k_cmfma<<<dim3(32, 16), 256, 0, stream>>>(oldbf, Wgbf, bg, zall, ypart);
  k_finalize<<<256, 256, 0, stream>>>(ypart, x, out, lossa);
}

// Round 14
// 224.633 us; speedup vs baseline: 1.2377x; 1.0700x over previous
//
#include <hip/hip_runtime.h>
#include <math.h>

#define B_   16
#define L_   128
#define O_   128
#define N_   256
#define S_   64
#define U_   32
#define DEL_ 64
#define HID_ 512
#define CH_  288          // N_+U_
#define M_   2048         // B_*L_
#define KD_  288          // GEMM K for the Wg projections
#define CM_BASE (DEL_ + N_*U_)   // 8256
#define NSLICE 32

typedef __bf16 bf16_t;
typedef bf16_t bf16x8 __attribute__((ext_vector_type(8)));
typedef float  f32x4  __attribute__((ext_vector_type(4)));

#define AS1(p) ((const __attribute__((address_space(1))) void*)(unsigned long long)(const void*)(p))
#define AS3(p) ((__attribute__((address_space(3))) void*)(unsigned int)(unsigned long long)(const void*)(p))

__device__ __forceinline__ float silu_f(float x){ return x / (1.f + expf(-x)); }
__device__ __forceinline__ float softplus_f(float x){
  return fmaxf(x, 0.f) + log1pf(expf(-fabsf(x)));
}

__device__ __forceinline__ void cvt8(const float* src, bf16_t* dst){
  float4 a = ((const float4*)src)[0];
  float4 b = ((const float4*)src)[1];
  bf16x8 o;
  o[0]=(bf16_t)a.x; o[1]=(bf16_t)a.y; o[2]=(bf16_t)a.z; o[3]=(bf16_t)a.w;
  o[4]=(bf16_t)b.x; o[5]=(bf16_t)b.y; o[6]=(bf16_t)b.z; o[7]=(bf16_t)b.w;
  *(bf16x8*)dst = o;
}

// ---------------- prep: Wg/W0/W1->bf16, x->bf16 packed, zero loss acc ----------------
#define CVT_BLOCKS 3465    // ceil(887040/256)  (Wg chunks of 8)
#define W0_BLOCKS  16      // 4096 chunks
#define W1_BLOCKS  64      // 16384 chunks
#define XB_BLOCKS  64      // 16384 chunks
__global__ void k_prep(const float* __restrict__ Wg, bf16_t* __restrict__ Wgbf,
                       const float* __restrict__ W0, bf16_t* __restrict__ W0bf,
                       const float* __restrict__ W1, bf16_t* __restrict__ W1bf,
                       const float* __restrict__ x,  bf16_t* __restrict__ xbf,
                       float* __restrict__ lossa){
  if (blockIdx.x == 0 && threadIdx.x < 2) lossa[threadIdx.x] = 0.f;
  if (blockIdx.x < CVT_BLOCKS) {
    int i = blockIdx.x*256 + threadIdx.x;
    if (i >= 887040) return;
    cvt8(Wg + (size_t)i*8, Wgbf + (size_t)i*8);
  } else if (blockIdx.x < CVT_BLOCKS + W0_BLOCKS) {
    int i = (blockIdx.x - CVT_BLOCKS)*256 + threadIdx.x;
    if (i >= 4096) return;
    cvt8(W0 + (size_t)i*8, W0bf + (size_t)i*8);
  } else if (blockIdx.x < CVT_BLOCKS + W0_BLOCKS + W1_BLOCKS) {
    int i = (blockIdx.x - CVT_BLOCKS - W0_BLOCKS)*256 + threadIdx.x;
    if (i >= 16384) return;
    cvt8(W1 + (size_t)i*8, W1bf + (size_t)i*8);
  } else {
    int i = (blockIdx.x - CVT_BLOCKS - W0_BLOCKS - W1_BLOCKS)*256 + threadIdx.x;
    if (i >= 16384) return;
    int m = i >> 3, c0 = (i & 7)*8;
    int b = m >> 7, t = m & 127;
    cvt8(x + (size_t)(((b<<8)+t)<<6) + c0, xbf + (size_t)m*64 + c0);
  }
}

// ================= 64x64 MFMA tile: fragment-order staging, BK=32 =================
// 4 waves; wave w stages A group w and B group w (16 rows x 32 k each, 1 KB).
// wave w computes quadrant (wm=w&1)*32 rows x (wn=w>>1)*32 cols via acc[2][2].
#define STAGE64(GBASE, ROW0G, STRIDE, LDSARR)                                        \
  { const bf16_t* gp = (GBASE) + (size_t)((ROW0G) + wave*16 + lm)*(STRIDE) + kk + lq*8; \
    __builtin_amdgcn_global_load_lds(AS1(gp), AS3(&(LDSARR)[wave*512]), 16, 0, 0); }

// ---------------- mlp1 MFMA: Hbf = relu(xbf @ W0bf.T + b0), K=64 ----------------
__global__ __launch_bounds__(256) void k_mlp1m(
    const bf16_t* __restrict__ xbf, const bf16_t* __restrict__ W0bf,
    const float* __restrict__ b0, bf16_t* __restrict__ Hbf){
  __shared__ __align__(16) bf16_t As[64*32];
  __shared__ __align__(16) bf16_t Bs[64*32];
  int tid = threadIdx.x;
  int wave = tid >> 6, lane = tid & 63;
  int wm = wave & 1, wn = wave >> 1;
  int nt = blockIdx.x, mt = blockIdx.y;
  int m0 = mt*64, n0 = nt*64;
  int lm = lane & 15, lq = lane >> 4;

  f32x4 acc[2][2];
  #pragma unroll
  for (int i=0;i<2;i++)
    #pragma unroll
    for (int j=0;j<2;j++){ acc[i][j][0]=0.f;acc[i][j][1]=0.f;acc[i][j][2]=0.f;acc[i][j][3]=0.f; }

  #pragma unroll
  for (int kk = 0; kk < 64; kk += 32) {
    STAGE64(xbf, m0, 64, As);
    STAGE64(W0bf, n0, 64, Bs);
    __syncthreads();
    bf16x8 af[2], bff[2];
    #pragma unroll
    for (int i=0;i<2;i++) af[i]  = *(const bf16x8*)&As[(wm*2 + i)*512 + lane*8];
    #pragma unroll
    for (int j=0;j<2;j++) bff[j] = *(const bf16x8*)&Bs[(wn*2 + j)*512 + lane*8];
    #pragma unroll
    for (int i=0;i<2;i++)
      #pragma unroll
      for (int j=0;j<2;j++)
        acc[i][j] = __builtin_amdgcn_mfma_f32_16x16x32_bf16(af[i], bff[j], acc[i][j], 0,0,0);
    __syncthreads();
  }
  #pragma unroll
  for (int i=0;i<2;i++)
    #pragma unroll
    for (int j=0;j<2;j++){
      int col = n0 + wn*32 + j*16 + lm;
      float bb = b0[col];
      #pragma unroll
      for (int r=0;r<4;r++){
        int row = m0 + wm*32 + i*16 + lq*4 + r;
        Hbf[(size_t)row*HID_ + col] = (bf16_t)fmaxf(acc[i][j][r] + bb, 0.f);
      }
    }
}

// ---------------- mlp2 MFMA: P = Hbf @ W1bf.T + b1, K=512, fp32 out ----------------
__global__ __launch_bounds__(256) void k_mlp2m(
    const bf16_t* __restrict__ Hbf, const bf16_t* __restrict__ W1bf,
    const float* __restrict__ b1, float* __restrict__ P){
  __shared__ __align__(16) bf16_t As[64*32];
  __shared__ __align__(16) bf16_t Bs[64*32];
  int tid = threadIdx.x;
  int wave = tid >> 6, lane = tid & 63;
  int wm = wave & 1, wn = wave >> 1;
  int nt = blockIdx.x, mt = blockIdx.y;
  int m0 = mt*64, n0 = nt*64;
  int lm = lane & 15, lq = lane >> 4;

  f32x4 acc[2][2];
  #pragma unroll
  for (int i=0;i<2;i++)
    #pragma unroll
    for (int j=0;j<2;j++){ acc[i][j][0]=0.f;acc[i][j][1]=0.f;acc[i][j][2]=0.f;acc[i][j][3]=0.f; }

  for (int kk = 0; kk < HID_; kk += 32) {
    STAGE64(Hbf, m0, HID_, As);
    STAGE64(W1bf, n0, HID_, Bs);
    __syncthreads();
    bf16x8 af[2], bff[2];
    #pragma unroll
    for (int i=0;i<2;i++) af[i]  = *(const bf16x8*)&As[(wm*2 + i)*512 + lane*8];
    #pragma unroll
    for (int j=0;j<2;j++) bff[j] = *(const bf16x8*)&Bs[(wn*2 + j)*512 + lane*8];
    #pragma unroll
    for (int i=0;i<2;i++)
      #pragma unroll
      for (int j=0;j<2;j++)
        acc[i][j] = __builtin_amdgcn_mfma_f32_16x16x32_bf16(af[i], bff[j], acc[i][j], 0,0,0);
    __syncthreads();
  }
  #pragma unroll
  for (int i=0;i<2;i++)
    #pragma unroll
    for (int j=0;j<2;j++){
      int col = n0 + wn*32 + j*16 + lm;
      float bb = b1[col];
      #pragma unroll
      for (int r=0;r<4;r++){
        int row = m0 + wm*32 + i*16 + lq*4 + r;
        P[(size_t)row*N_ + col] = acc[i][j][r] + bb;
      }
    }
}

// ---------------- fused conv + delta, 4 rows/block (512 blocks) ----------------
__global__ __launch_bounds__(256) void k_convdelta(
    const float* __restrict__ P, const float* __restrict__ u,
    const float* __restrict__ cw, const float* __restrict__ cb,
    const float* __restrict__ Wg, const float* __restrict__ bg,
    const float* __restrict__ Wdt, const float* __restrict__ bdt,
    const float* __restrict__ Ap, bf16_t* __restrict__ oldbf,
    float* __restrict__ dA, float* __restrict__ coef){
  __shared__ __align__(16) float olds[4*KD_];
  __shared__ float dr[4][64];
  int tid = threadIdx.x;
  int m0 = blockIdx.x * 4;
  int b = m0 >> 7, l0 = m0 & 127;
  for (int e = tid; e < 4*CH_; e += 256) {
    int r = e / CH_, c = e - r*CH_;
    int l = l0 + r;
    float acc = cb[c];
    #pragma unroll
    for (int k = 0; k < 4; k++) {
      int t = l + k - 1;
      if (t >= 0 && t <= O_-2) {
        float s = (c < N_) ? P[((b<<7)+t)*N_ + c] : u[((b<<8)+t)*U_ + (c-N_)];
        acc += silu_f(s) * cw[c*4 + k];
      }
    }
    float v = silu_f(acc);
    olds[e] = v;
    oldbf[(size_t)(m0+r)*CH_ + c] = (bf16_t)v;
  }
  __syncthreads();
  {
    int d = tid & 63;
    int r = tid >> 6;
    const float* wrow = Wg + (size_t)d*KD_;
    const float* orow = olds + r*KD_;
    float s = 0.f;
    for (int k = 0; k < KD_; k++) s += orow[k] * wrow[k];
    dr[r][d] = s + bg[d];
  }
  __syncthreads();
  int n = tid;
  float wrow[64];
  #pragma unroll
  for (int d = 0; d < 64; d++) wrow[d] = Wdt[n*64 + d];
  float a0 = Ap[n];
  float a = -(a0 > 0.f ? a0 : expm1f(a0));
  float inva = 1.f / a;
  float bd = bdt[n];
  #pragma unroll
  for (int r = 0; r < 4; r++) {
    float s = bd;
    #pragma unroll
    for (int d = 0; d < 64; d++) s += dr[r][d] * wrow[d];
    float dd = softplus_f(s);
    float e  = expf(dd * a);
    size_t m = m0 + r;
    dA[m*N_ + n]   = e;
    coef[m*N_ + n] = (e - 1.f) * inva;
  }
}

// ================= fragment-order staging, BK=96 (3 col-blocks of 32) =================
#define STAGE_FR96(GBASE, ROW0G, LDSARR)                                                 \
  { _Pragma("unroll")                                                                    \
    for (int c = 0; c < 3; c++) {                                                        \
      _Pragma("unroll")                                                                  \
      for (int q = 0; q < 2; q++) {                                                      \
        int g = wave*2 + q;                                                              \
        const bf16_t* gp = (GBASE) + (size_t)((ROW0G) + g*16 + lm)*KD_ + kk + c*32 + lq*8;\
        __builtin_amdgcn_global_load_lds(AS1(gp), AS3(&(LDSARR)[c*4096 + g*512]), 16, 0, 0);\
      } } }

// ---------------- B-path MFMA (BK=96) + fused Kogge-Stone scan -> zall ----------------
__global__ __launch_bounds__(256, 2) void k_bmfma(
    const bf16_t* __restrict__ oldbf, const bf16_t* __restrict__ Wgbf,
    const float* __restrict__ bg, const float* __restrict__ u,
    const float* __restrict__ coef, const float* __restrict__ dAg,
    const float* __restrict__ Pg, float* __restrict__ zall){
  __shared__ union {
    struct { __align__(16) bf16_t A[3*4096]; __align__(16) bf16_t B[3*4096]; } st;
    struct { float wl[128][4]; float dal[128][4]; } sc;   // 4 KB, used post-GEMM
  } sm;
  int tid = threadIdx.x;
  int wave = tid >> 6, lane = tid & 63;
  int wm = wave & 1, wn = wave >> 1;
  int mt = blockIdx.y, nt = blockIdx.x;
  int m0 = mt*128, ncol0 = nt*128;
  int lm = lane & 15, lq = lane >> 4;

  f32x4 acc[4][4];
  #pragma unroll
  for (int i=0;i<4;i++)
    #pragma unroll
    for (int j=0;j<4;j++){ acc[i][j][0]=0.f;acc[i][j][1]=0.f;acc[i][j][2]=0.f;acc[i][j][3]=0.f; }

  for (int kk = 0; kk < KD_; kk += 96) {
    STAGE_FR96(oldbf, m0, sm.st.A);
    STAGE_FR96(Wgbf, DEL_ + ncol0, sm.st.B);
    __syncthreads();
    for (int c = 0; c < 3; c++) {
      bf16x8 af[4], bff[4];
      #pragma unroll
      for (int i=0;i<4;i++) af[i]  = *(const bf16x8*)&sm.st.A[c*4096 + (wm*4 + i)*512 + lane*8];
      #pragma unroll
      for (int j=0;j<4;j++) bff[j] = *(const bf16x8*)&sm.st.B[c*4096 + (wn*4 + j)*512 + lane*8];
      #pragma unroll
      for (int i=0;i<4;i++)
        #pragma unroll
        for (int j=0;j<4;j++)
          acc[i][j] = __builtin_amdgcn_mfma_f32_16x16x32_bf16(af[i], bff[j], acc[i][j], 0,0,0);
    }
    __syncthreads();
  }

  // staging LDS dead: preload dA columns for the fused scan
  for (int e = tid; e < 512; e += 256)
    sm.sc.dal[e>>2][e&3] = dAg[(size_t)(m0 + (e>>2))*N_ + nt*4 + (e&3)];

  float bgv[4];
  #pragma unroll
  for (int j=0;j<4;j++) bgv[j] = bg[DEL_ + ncol0 + wn*64 + j*16 + lm];
  float p[2][4][4];
  #pragma unroll
  for (int a=0;a<2;a++)
    #pragma unroll
    for (int i=0;i<4;i++)
      #pragma unroll
      for (int r=0;r<4;r++) p[a][i][r]=0.f;
  #pragma unroll
  for (int i=0;i<4;i++){
    #pragma unroll
    for (int r=0;r<4;r++){
      int m = m0 + wm*64 + i*16 + lq*4 + r;
      int b = m >> 7, l = m & 127;
      const float* urow = u + ((size_t)(b<<8) + 127 + l)*U_;
      #pragma unroll
      for (int j=0;j<4;j++){
        float uu = urow[(j&1)*16 + lm];
        p[j>>1][i][r] += (acc[i][j][r] + bgv[j]) * uu;
      }
    }
  }
  #pragma unroll
  for (int mk = 1; mk < 16; mk <<= 1){
    #pragma unroll
    for (int a=0;a<2;a++)
      #pragma unroll
      for (int i=0;i<4;i++)
        #pragma unroll
        for (int r=0;r<4;r++) p[a][i][r] += __shfl_xor(p[a][i][r], mk);
  }
  if (lm == 0){
    #pragma unroll
    for (int nl=0;nl<2;nl++){
      int n = ((ncol0 + wn*64 + nl*32) >> 5);
      int nc = wn*2 + nl;
      #pragma unroll
      for (int i=0;i<4;i++)
        #pragma unroll
        for (int r=0;r<4;r++){
          int l = wm*64 + i*16 + lq*4 + r;
          sm.sc.wl[l][nc] = coef[(size_t)(m0+l)*N_ + n] * p[nl][i][r];
        }
    }
  }
  __syncthreads();

  // fused scan: wave = n-column; 2 l per lane, Kogge-Stone over pair affines
  {
    int nc = wave;
    int n = nt*4 + nc;
    float z0 = Pg[(size_t)(m0 + 127)*N_ + n];
    int l0 = lane*2;
    float a0 = sm.sc.dal[l0][nc],   w0 = sm.sc.wl[l0][nc];
    float a1 = sm.sc.dal[l0+1][nc], w1 = sm.sc.wl[l0+1][nc];
    float A = a0*a1, Bv = w0*a1 + w1;
    #pragma unroll
    for (int d = 1; d < 64; d <<= 1){
      float Ap = __shfl_up(A, d);
      float Bp = __shfl_up(Bv, d);
      if (lane >= d){ Bv = Bp*A + Bv; A = Ap*A; }
    }
    float Ae = __shfl_up(A, 1);
    float Be = __shfl_up(Bv, 1);
    if (lane == 0){ Ae = 1.f; Be = 0.f; }
    float zp = z0*Ae + Be;
    float za = zp*a0 + w0;
    float zb = za*a1 + w1;
    zall[(size_t)(m0 + l0)*N_ + n]     = za;
    zall[(size_t)(m0 + l0 + 1)*N_ + n] = zb;
  }
}

// ---------------- C-path MFMA (BK=96): 4 n-tiles/block, per-block y slice ----------------
__global__ __launch_bounds__(256, 2) void k_cmfma(
    const bf16_t* __restrict__ oldbf, const bf16_t* __restrict__ Wgbf,
    const float* __restrict__ bg, const float* __restrict__ zall,
    float* __restrict__ ypart){
  __shared__ union {
    struct { bf16_t A[3*4096]; bf16_t B[3*4096]; } st;   // 48 KB staging
    float ylds[128][64];                                  // 32 KB (after staging dead)
  } sm;
  int tid = threadIdx.x;
  int wave = tid >> 6, lane = tid & 63;
  int wm = wave & 1, wn = wave >> 1;
  int mt = blockIdx.y, grp = blockIdx.x;   // 32 groups of 4 n-tiles
  int m0 = mt*128;
  int lm = lane & 15, lq = lane >> 4;

  f32x4 yacc[4][4];
  #pragma unroll
  for (int i=0;i<4;i++)
    #pragma unroll
    for (int j=0;j<4;j++){ yacc[i][j][0]=0.f;yacc[i][j][1]=0.f;yacc[i][j][2]=0.f;yacc[i][j][3]=0.f; }

  for (int it = 0; it < 4; it++) {
    int ncol0 = (grp*4 + it)*128;
    f32x4 acc[4][4];
    #pragma unroll
    for (int i=0;i<4;i++)
      #pragma unroll
      for (int j=0;j<4;j++){ acc[i][j][0]=0.f;acc[i][j][1]=0.f;acc[i][j][2]=0.f;acc[i][j][3]=0.f; }

    for (int kk = 0; kk < KD_; kk += 96) {
      STAGE_FR96(oldbf, m0, sm.st.A);
      STAGE_FR96(Wgbf, CM_BASE + ncol0, sm.st.B);
      __syncthreads();
      for (int c = 0; c < 3; c++) {
        bf16x8 af[4], bff[4];
        #pragma unroll
        for (int i=0;i<4;i++) af[i]  = *(const bf16x8*)&sm.st.A[c*4096 + (wm*4 + i)*512 + lane*8];
        #pragma unroll
        for (int j=0;j<4;j++) bff[j] = *(const bf16x8*)&sm.st.B[c*4096 + (wn*4 + j)*512 + lane*8];
        #pragma unroll
        for (int i=0;i<4;i++)
          #pragma unroll
          for (int j=0;j<4;j++)
            acc[i][j] = __builtin_amdgcn_mfma_f32_16x16x32_bf16(af[i], bff[j], acc[i][j], 0,0,0);
      }
      __syncthreads();
    }

    int n = (ncol0 >> 6) + wn;
    float bgv[4];
    #pragma unroll
    for (int j=0;j<4;j++) bgv[j] = bg[CM_BASE + ncol0 + wn*64 + j*16 + lm];
    #pragma unroll
    for (int i=0;i<4;i++){
      #pragma unroll
      for (int r=0;r<4;r++){
        int m = m0 + wm*64 + i*16 + lq*4 + r;
        float zv = zall[(size_t)m*N_ + n];
        #pragma unroll
        for (int j=0;j<4;j++)
          yacc[i][j][r] += (acc[i][j][r] + bgv[j]) * zv;
      }
    }
  }

  __syncthreads();
  if (wn == 1){
    #pragma unroll
    for (int i=0;i<4;i++)
      #pragma unroll
      for (int j=0;j<4;j++)
        #pragma unroll
        for (int r=0;r<4;r++){
          int ml = wm*64 + i*16 + lq*4 + r;
          sm.ylds[ml][j*16 + lm] = yacc[i][j][r];
        }
  }
  __syncthreads();
  if (wn == 0){
    float* dst = ypart + (size_t)grp*(M_*S_);
    #pragma unroll
    for (int i=0;i<4;i++)
      #pragma unroll
      for (int j=0;j<4;j++)
        #pragma unroll
        for (int r=0;r<4;r++){
          int ml = wm*64 + i*16 + lq*4 + r;
          int s = j*16 + lm;
          dst[(size_t)(m0+ml)*S_ + s] = yacc[i][j][r] + sm.ylds[ml][s];
        }
  }
}

// ---------------- finalize: sum slices, write ys (L,B,S), fused loss ----------------
__global__ void k_finalize(const float* __restrict__ ypart, const float* __restrict__ x,
                           float* __restrict__ out, float* __restrict__ lossacc){
  __shared__ float red[256];
  int tid = threadIdx.x;
  float ls = 0.f;
  #pragma unroll
  for (int q = 0; q < 2; q++) {
    int e = blockIdx.x*512 + q*256 + tid;
    int m = e >> 6, s = e & 63;
    int b = m >> 7, l = m & 127;
    float yv = 0.f;
    #pragma unroll 8
    for (int g = 0; g < NSLICE; g++) yv += ypart[(size_t)g*(M_*S_) + e];
    out[1 + (size_t)((l<<4) + b)*S_ + s] = yv;
    float xv = x[((size_t)(b<<8) + 128 + l)*S_ + s];
    float d = yv - xv;
    ls += d*d;
  }
  red[tid] = ls; __syncthreads();
  for (int st = 128; st > 0; st >>= 1) {
    if (tid < st) red[tid] += red[tid+st];
    __syncthreads();
  }
  if (tid == 0) {
    atomicAdd(&lossacc[0], red[0]);
    __threadfence();
    unsigned old = atomicAdd((unsigned*)&lossacc[1], 1u);
    if (old == 255u) {
      float tot = atomicAdd(&lossacc[0], 0.f);   // atomic read (bypass L1)
      out[0] = tot * (1.f / (float)(B_*S_*L_));
    }
  }
}

extern "C" void kernel_launch(void* const* d_in, const int* in_sizes, int n_in,
                              void* d_out, int out_size, void* d_ws, size_t ws_size,
                              hipStream_t stream) {
  const float* x   = (const float*)d_in[0];
  const float* u   = (const float*)d_in[1];
  const float* Ap  = (const float*)d_in[2];
  const float* W0  = (const float*)d_in[3];
  const float* b0  = (const float*)d_in[4];
  const float* W1  = (const float*)d_in[5];
  const float* b1  = (const float*)d_in[6];
  const float* cw  = (const float*)d_in[7];
  const float* cb  = (const float*)d_in[8];
  const float* Wg  = (const float*)d_in[9];
  const float* bg  = (const float*)d_in[10];
  const float* Wdt = (const float*)d_in[11];
  const float* bdt = (const float*)d_in[12];
  float* out = (float*)d_out;

  // Layout: persistent buffers first; region R of fp32 temps (all dead before
  // k_cmfma) is overlaid by ypart (32 slices = 16 MB).
  float* ws    = (float*)d_ws;
  float* zall  = ws;                        // 524288
  float* lossa = zall + 524288;             // 512 (acc, counter)
  bf16_t* oldbf = (bf16_t*)(lossa + 512);   // 294912 f32 slots
  bf16_t* Wgbf  = (bf16_t*)(lossa + 512 + 294912);              // 3548160 slots
  bf16_t* W0bf  = (bf16_t*)(lossa + 512 + 294912 + 3548160);    // 16384 slots
  bf16_t* W1bf  = (bf16_t*)(lossa + 512 + 294912 + 3548160 + 16384);   // 65536 slots
  bf16_t* xbf   = (bf16_t*)(lossa + 512 + 294912 + 3548160 + 16384 + 65536); // 65536 slots
  bf16_t* Hbf   = (bf16_t*)(lossa + 512 + 294912 + 3548160 + 16384 + 65536 + 65536); // 524288 slots
  float* R     = lossa + 512 + 294912 + 3548160 + 16384 + 65536 + 65536 + 524288;
  float* Pp    = R;                         // 524288
  float* dA    = Pp   + 524288;             // 524288
  float* coef  = dA   + 524288;             // 524288
  float* ypart = R;                         // 32*131072 = 4194304, overlays R... 
  // NOTE: Pp/dA/coef are dead before k_cmfma (convdelta+bmfma consume them);
  // ypart overlays R and extends past it into free workspace (as in R5-R13).

  k_prep<<<CVT_BLOCKS + W0_BLOCKS + W1_BLOCKS + XB_BLOCKS, 256, 0, stream>>>(
      Wg, Wgbf, W0, W0bf, W1, W1bf, x, xbf, lossa);
  k_mlp1m<<<dim3(HID_/64, M_/64), 256, 0, stream>>>(xbf, W0bf, b0, Hbf);
  k_mlp2m<<<dim3(N_/64, M_/64), 256, 0, stream>>>(Hbf, W1bf, b1, Pp);
  k_convdelta<<<M_/4, 256, 0, stream>>>(Pp, u, cw, cb, Wg, bg, Wdt, bdt, Ap,
                                        oldbf, dA, coef);
  k_bmfma<<<dim3(64, 16), 256, 0, stream>>>(oldbf, Wgbf, bg, u, coef, dA, Pp, zall);
  k_cmfma<<<dim3(32, 16), 256, 0, stream>>>(oldbf, Wgbf, bg, zall, ypart);
  k_finalize<<<256, 256, 0, stream>>>(ypart, x, out, lossa);
}

// Round 15
// 213.205 us; speedup vs baseline: 1.3041x; 1.0536x over previous
//
#include <hip/hip_runtime.h>
#include <math.h>

#define B_   16
#define L_   128
#define O_   128
#define N_   256
#define S_   64
#define U_   32
#define DEL_ 64
#define HID_ 512
#define CH_  288          // N_+U_
#define M_   2048         // B_*L_
#define KD_  288          // GEMM K for the Wg projections
#define CM_BASE (DEL_ + N_*U_)   // 8256
#define NSLICE 32

typedef __bf16 bf16_t;
typedef bf16_t bf16x8 __attribute__((ext_vector_type(8)));
typedef float  f32x4  __attribute__((ext_vector_type(4)));

#define AS1(p) ((const __attribute__((address_space(1))) void*)(unsigned long long)(const void*)(p))
#define AS3(p) ((__attribute__((address_space(3))) void*)(unsigned int)(unsigned long long)(const void*)(p))

__device__ __forceinline__ float silu_f(float x){ return x / (1.f + expf(-x)); }
__device__ __forceinline__ float softplus_f(float x){
  return fmaxf(x, 0.f) + log1pf(expf(-fabsf(x)));
}

__device__ __forceinline__ void cvt8(const float* src, bf16_t* dst){
  float4 a = ((const float4*)src)[0];
  float4 b = ((const float4*)src)[1];
  bf16x8 o;
  o[0]=(bf16_t)a.x; o[1]=(bf16_t)a.y; o[2]=(bf16_t)a.z; o[3]=(bf16_t)a.w;
  o[4]=(bf16_t)b.x; o[5]=(bf16_t)b.y; o[6]=(bf16_t)b.z; o[7]=(bf16_t)b.w;
  *(bf16x8*)dst = o;
}

// ---------------- prep: Wg/W0/W1->bf16, x->bf16 packed, zero loss acc ----------------
#define CVT_BLOCKS 3465    // ceil(887040/256)  (Wg chunks of 8)
#define W0_BLOCKS  16      // 4096 chunks
#define W1_BLOCKS  64      // 16384 chunks
#define XB_BLOCKS  64      // 16384 chunks
__global__ void k_prep(const float* __restrict__ Wg, bf16_t* __restrict__ Wgbf,
                       const float* __restrict__ W0, bf16_t* __restrict__ W0bf,
                       const float* __restrict__ W1, bf16_t* __restrict__ W1bf,
                       const float* __restrict__ x,  bf16_t* __restrict__ xbf,
                       float* __restrict__ lossa){
  if (blockIdx.x == 0 && threadIdx.x < 2) lossa[threadIdx.x] = 0.f;
  if (blockIdx.x < CVT_BLOCKS) {
    int i = blockIdx.x*256 + threadIdx.x;
    if (i >= 887040) return;
    cvt8(Wg + (size_t)i*8, Wgbf + (size_t)i*8);
  } else if (blockIdx.x < CVT_BLOCKS + W0_BLOCKS) {
    int i = (blockIdx.x - CVT_BLOCKS)*256 + threadIdx.x;
    if (i >= 4096) return;
    cvt8(W0 + (size_t)i*8, W0bf + (size_t)i*8);
  } else if (blockIdx.x < CVT_BLOCKS + W0_BLOCKS + W1_BLOCKS) {
    int i = (blockIdx.x - CVT_BLOCKS - W0_BLOCKS)*256 + threadIdx.x;
    if (i >= 16384) return;
    cvt8(W1 + (size_t)i*8, W1bf + (size_t)i*8);
  } else {
    int i = (blockIdx.x - CVT_BLOCKS - W0_BLOCKS - W1_BLOCKS)*256 + threadIdx.x;
    if (i >= 16384) return;
    int m = i >> 3, c0 = (i & 7)*8;
    int b = m >> 7, t = m & 127;
    cvt8(x + (size_t)(((b<<8)+t)<<6) + c0, xbf + (size_t)m*64 + c0);
  }
}

// ================= 64x64 MFMA tile: fragment-order staging, BK=32 =================
#define STAGE64(GBASE, ROW0G, STRIDE, LDSARR)                                        \
  { const bf16_t* gp = (GBASE) + (size_t)((ROW0G) + wave*16 + lm)*(STRIDE) + kk + lq*8; \
    __builtin_amdgcn_global_load_lds(AS1(gp), AS3(&(LDSARR)[wave*512]), 16, 0, 0); }

// ---------------- mlp1 MFMA: Hbf = relu(xbf @ W0bf.T + b0), K=64 ----------------
__global__ __launch_bounds__(256) void k_mlp1m(
    const bf16_t* __restrict__ xbf, const bf16_t* __restrict__ W0bf,
    const float* __restrict__ b0, bf16_t* __restrict__ Hbf){
  __shared__ __align__(16) bf16_t As[64*32];
  __shared__ __align__(16) bf16_t Bs[64*32];
  int tid = threadIdx.x;
  int wave = tid >> 6, lane = tid & 63;
  int wm = wave & 1, wn = wave >> 1;
  int nt = blockIdx.x, mt = blockIdx.y;
  int m0 = mt*64, n0 = nt*64;
  int lm = lane & 15, lq = lane >> 4;

  f32x4 acc[2][2];
  #pragma unroll
  for (int i=0;i<2;i++)
    #pragma unroll
    for (int j=0;j<2;j++){ acc[i][j][0]=0.f;acc[i][j][1]=0.f;acc[i][j][2]=0.f;acc[i][j][3]=0.f; }

  #pragma unroll
  for (int kk = 0; kk < 64; kk += 32) {
    STAGE64(xbf, m0, 64, As);
    STAGE64(W0bf, n0, 64, Bs);
    __syncthreads();
    bf16x8 af[2], bff[2];
    #pragma unroll
    for (int i=0;i<2;i++) af[i]  = *(const bf16x8*)&As[(wm*2 + i)*512 + lane*8];
    #pragma unroll
    for (int j=0;j<2;j++) bff[j] = *(const bf16x8*)&Bs[(wn*2 + j)*512 + lane*8];
    #pragma unroll
    for (int i=0;i<2;i++)
      #pragma unroll
      for (int j=0;j<2;j++)
        acc[i][j] = __builtin_amdgcn_mfma_f32_16x16x32_bf16(af[i], bff[j], acc[i][j], 0,0,0);
    __syncthreads();
  }
  #pragma unroll
  for (int i=0;i<2;i++)
    #pragma unroll
    for (int j=0;j<2;j++){
      int col = n0 + wn*32 + j*16 + lm;
      float bb = b0[col];
      #pragma unroll
      for (int r=0;r<4;r++){
        int row = m0 + wm*32 + i*16 + lq*4 + r;
        Hbf[(size_t)row*HID_ + col] = (bf16_t)fmaxf(acc[i][j][r] + bb, 0.f);
      }
    }
}

// ---------------- mlp2 MFMA: P = Hbf @ W1bf.T + b1, K=512, fp32 out ----------------
__global__ __launch_bounds__(256) void k_mlp2m(
    const bf16_t* __restrict__ Hbf, const bf16_t* __restrict__ W1bf,
    const float* __restrict__ b1, float* __restrict__ P){
  __shared__ __align__(16) bf16_t As[64*32];
  __shared__ __align__(16) bf16_t Bs[64*32];
  int tid = threadIdx.x;
  int wave = tid >> 6, lane = tid & 63;
  int wm = wave & 1, wn = wave >> 1;
  int nt = blockIdx.x, mt = blockIdx.y;
  int m0 = mt*64, n0 = nt*64;
  int lm = lane & 15, lq = lane >> 4;

  f32x4 acc[2][2];
  #pragma unroll
  for (int i=0;i<2;i++)
    #pragma unroll
    for (int j=0;j<2;j++){ acc[i][j][0]=0.f;acc[i][j][1]=0.f;acc[i][j][2]=0.f;acc[i][j][3]=0.f; }

  for (int kk = 0; kk < HID_; kk += 32) {
    STAGE64(Hbf, m0, HID_, As);
    STAGE64(W1bf, n0, HID_, Bs);
    __syncthreads();
    bf16x8 af[2], bff[2];
    #pragma unroll
    for (int i=0;i<2;i++) af[i]  = *(const bf16x8*)&As[(wm*2 + i)*512 + lane*8];
    #pragma unroll
    for (int j=0;j<2;j++) bff[j] = *(const bf16x8*)&Bs[(wn*2 + j)*512 + lane*8];
    #pragma unroll
    for (int i=0;i<2;i++)
      #pragma unroll
      for (int j=0;j<2;j++)
        acc[i][j] = __builtin_amdgcn_mfma_f32_16x16x32_bf16(af[i], bff[j], acc[i][j], 0,0,0);
    __syncthreads();
  }
  #pragma unroll
  for (int i=0;i<2;i++)
    #pragma unroll
    for (int j=0;j<2;j++){
      int col = n0 + wn*32 + j*16 + lm;
      float bb = b1[col];
      #pragma unroll
      for (int r=0;r<4;r++){
        int row = m0 + wm*32 + i*16 + lq*4 + r;
        P[(size_t)row*N_ + col] = acc[i][j][r] + bb;
      }
    }
}

// ---------------- fused conv + delta, 4 rows/block (512 blocks) ----------------
__global__ __launch_bounds__(256) void k_convdelta(
    const float* __restrict__ P, const float* __restrict__ u,
    const float* __restrict__ cw, const float* __restrict__ cb,
    const float* __restrict__ Wg, const float* __restrict__ bg,
    const float* __restrict__ Wdt, const float* __restrict__ bdt,
    const float* __restrict__ Ap, bf16_t* __restrict__ oldbf,
    float* __restrict__ dA, float* __restrict__ coef){
  __shared__ __align__(16) float olds[4*KD_];
  __shared__ float dr[4][64];
  int tid = threadIdx.x;
  int m0 = blockIdx.x * 4;
  int b = m0 >> 7, l0 = m0 & 127;
  for (int e = tid; e < 4*CH_; e += 256) {
    int r = e / CH_, c = e - r*CH_;
    int l = l0 + r;
    float acc = cb[c];
    #pragma unroll
    for (int k = 0; k < 4; k++) {
      int t = l + k - 1;
      if (t >= 0 && t <= O_-2) {
        float s = (c < N_) ? P[((b<<7)+t)*N_ + c] : u[((b<<8)+t)*U_ + (c-N_)];
        acc += silu_f(s) * cw[c*4 + k];
      }
    }
    float v = silu_f(acc);
    olds[e] = v;
    oldbf[(size_t)(m0+r)*CH_ + c] = (bf16_t)v;
  }
  __syncthreads();
  {
    int d = tid & 63;
    int r = tid >> 6;
    const float* wrow = Wg + (size_t)d*KD_;
    const float* orow = olds + r*KD_;
    float s = 0.f;
    for (int k = 0; k < KD_; k++) s += orow[k] * wrow[k];
    dr[r][d] = s + bg[d];
  }
  __syncthreads();
  int n = tid;
  float wrow[64];
  #pragma unroll
  for (int d = 0; d < 64; d++) wrow[d] = Wdt[n*64 + d];
  float a0 = Ap[n];
  float a = -(a0 > 0.f ? a0 : expm1f(a0));
  float inva = 1.f / a;
  float bd = bdt[n];
  #pragma unroll
  for (int r = 0; r < 4; r++) {
    float s = bd;
    #pragma unroll
    for (int d = 0; d < 64; d++) s += dr[r][d] * wrow[d];
    float dd = softplus_f(s);
    float e  = expf(dd * a);
    size_t m = m0 + r;
    dA[m*N_ + n]   = e;
    coef[m*N_ + n] = (e - 1.f) * inva;
  }
}

// ================= fragment-order staging, 128x96 tile (3 col-blocks of 32) =================
#define STAGE_FR96(GBASE, ROW0G, LDSARR)                                                 \
  { _Pragma("unroll")                                                                    \
    for (int c = 0; c < 3; c++) {                                                        \
      _Pragma("unroll")                                                                  \
      for (int q = 0; q < 2; q++) {                                                      \
        int g = wave*2 + q;                                                              \
        const bf16_t* gp = (GBASE) + (size_t)((ROW0G) + g*16 + lm)*KD_ + kk + c*32 + lq*8;\
        __builtin_amdgcn_global_load_lds(AS1(gp), AS3(&(LDSARR)[c*4096 + g*512]), 16, 0, 0);\
      } } }

// ---------------- B-path MFMA (BK=96) + fused Kogge-Stone scan -> zall ----------------
__global__ __launch_bounds__(256, 2) void k_bmfma(
    const bf16_t* __restrict__ oldbf, const bf16_t* __restrict__ Wgbf,
    const float* __restrict__ bg, const float* __restrict__ u,
    const float* __restrict__ coef, const float* __restrict__ dAg,
    const float* __restrict__ Pg, float* __restrict__ zall){
  __shared__ union {
    struct { __align__(16) bf16_t A[3*4096]; __align__(16) bf16_t B[3*4096]; } st;
    struct { float wl[128][4]; float dal[128][4]; } sc;   // 4 KB, used post-GEMM
  } sm;
  int tid = threadIdx.x;
  int wave = tid >> 6, lane = tid & 63;
  int wm = wave & 1, wn = wave >> 1;
  int mt = blockIdx.y, nt = blockIdx.x;
  int m0 = mt*128, ncol0 = nt*128;
  int lm = lane & 15, lq = lane >> 4;

  f32x4 acc[4][4];
  #pragma unroll
  for (int i=0;i<4;i++)
    #pragma unroll
    for (int j=0;j<4;j++){ acc[i][j][0]=0.f;acc[i][j][1]=0.f;acc[i][j][2]=0.f;acc[i][j][3]=0.f; }

  for (int kk = 0; kk < KD_; kk += 96) {
    STAGE_FR96(oldbf, m0, sm.st.A);
    STAGE_FR96(Wgbf, DEL_ + ncol0, sm.st.B);
    __syncthreads();
    for (int c = 0; c < 3; c++) {
      bf16x8 af[4], bff[4];
      #pragma unroll
      for (int i=0;i<4;i++) af[i]  = *(const bf16x8*)&sm.st.A[c*4096 + (wm*4 + i)*512 + lane*8];
      #pragma unroll
      for (int j=0;j<4;j++) bff[j] = *(const bf16x8*)&sm.st.B[c*4096 + (wn*4 + j)*512 + lane*8];
      #pragma unroll
      for (int i=0;i<4;i++)
        #pragma unroll
        for (int j=0;j<4;j++)
          acc[i][j] = __builtin_amdgcn_mfma_f32_16x16x32_bf16(af[i], bff[j], acc[i][j], 0,0,0);
    }
    __syncthreads();
  }

  // staging LDS dead: preload dA columns for the fused scan
  for (int e = tid; e < 512; e += 256)
    sm.sc.dal[e>>2][e&3] = dAg[(size_t)(m0 + (e>>2))*N_ + nt*4 + (e&3)];

  float bgv[4];
  #pragma unroll
  for (int j=0;j<4;j++) bgv[j] = bg[DEL_ + ncol0 + wn*64 + j*16 + lm];
  float p[2][4][4];
  #pragma unroll
  for (int a=0;a<2;a++)
    #pragma unroll
    for (int i=0;i<4;i++)
      #pragma unroll
      for (int r=0;r<4;r++) p[a][i][r]=0.f;
  #pragma unroll
  for (int i=0;i<4;i++){
    #pragma unroll
    for (int r=0;r<4;r++){
      int m = m0 + wm*64 + i*16 + lq*4 + r;
      int b = m >> 7, l = m & 127;
      const float* urow = u + ((size_t)(b<<8) + 127 + l)*U_;
      #pragma unroll
      for (int j=0;j<4;j++){
        float uu = urow[(j&1)*16 + lm];
        p[j>>1][i][r] += (acc[i][j][r] + bgv[j]) * uu;
      }
    }
  }
  #pragma unroll
  for (int mk = 1; mk < 16; mk <<= 1){
    #pragma unroll
    for (int a=0;a<2;a++)
      #pragma unroll
      for (int i=0;i<4;i++)
        #pragma unroll
        for (int r=0;r<4;r++) p[a][i][r] += __shfl_xor(p[a][i][r], mk);
  }
  if (lm == 0){
    #pragma unroll
    for (int nl=0;nl<2;nl++){
      int n = ((ncol0 + wn*64 + nl*32) >> 5);
      int nc = wn*2 + nl;
      #pragma unroll
      for (int i=0;i<4;i++)
        #pragma unroll
        for (int r=0;r<4;r++){
          int l = wm*64 + i*16 + lq*4 + r;
          sm.sc.wl[l][nc] = coef[(size_t)(m0+l)*N_ + n] * p[nl][i][r];
        }
    }
  }
  __syncthreads();

  // fused scan: wave = n-column; 2 l per lane, Kogge-Stone over pair affines
  {
    int nc = wave;
    int n = nt*4 + nc;
    float z0 = Pg[(size_t)(m0 + 127)*N_ + n];
    int l0 = lane*2;
    float a0 = sm.sc.dal[l0][nc],   w0 = sm.sc.wl[l0][nc];
    float a1 = sm.sc.dal[l0+1][nc], w1 = sm.sc.wl[l0+1][nc];
    float A = a0*a1, Bv = w0*a1 + w1;
    #pragma unroll
    for (int d = 1; d < 64; d <<= 1){
      float Ap = __shfl_up(A, d);
      float Bp = __shfl_up(Bv, d);
      if (lane >= d){ Bv = Bp*A + Bv; A = Ap*A; }
    }
    float Ae = __shfl_up(A, 1);
    float Be = __shfl_up(Bv, 1);
    if (lane == 0){ Ae = 1.f; Be = 0.f; }
    float zp = z0*Ae + Be;
    float za = zp*a0 + w0;
    float zb = za*a1 + w1;
    zall[(size_t)(m0 + l0)*N_ + n]     = za;
    zall[(size_t)(m0 + l0 + 1)*N_ + n] = zb;
  }
}

// ---------------- C-path MFMA v3: A resident per K-third, B-only inner staging ----------------
// kh outer (3 K-thirds): stage A third once; it inner (4 n-tiles): stage B only.
// y-contraction is kh-partial (linear in C); bg added only on last kh.
// z preloaded to LDS (128 x 8 per block).
__global__ __launch_bounds__(256, 2) void k_cmfma(
    const bf16_t* __restrict__ oldbf, const bf16_t* __restrict__ Wgbf,
    const float* __restrict__ bg, const float* __restrict__ zall,
    float* __restrict__ ypart){
  __shared__ union {
    struct { __align__(16) bf16_t A[3*4096];   // 24 KB, resident per kh
             __align__(16) bf16_t Bb[3*4096];  // 24 KB, per (kh,it)
             float zl[128][8]; } st;           // 4 KB
    float ylds[128][64];                        // 32 KB, used at the end
  } sm;
  int tid = threadIdx.x;
  int wave = tid >> 6, lane = tid & 63;
  int wm = wave & 1, wn = wave >> 1;
  int mt = blockIdx.y, grp = blockIdx.x;   // 32 groups of 4 n-tiles
  int m0 = mt*128;
  int lm = lane & 15, lq = lane >> 4;

  // preload z block: 128 m x 8 n
  for (int e = tid; e < 1024; e += 256)
    sm.st.zl[e>>3][e&7] = zall[(size_t)(m0 + (e>>3))*N_ + grp*8 + (e&7)];

  f32x4 yacc[4][4];
  #pragma unroll
  for (int i=0;i<4;i++)
    #pragma unroll
    for (int j=0;j<4;j++){ yacc[i][j][0]=0.f;yacc[i][j][1]=0.f;yacc[i][j][2]=0.f;yacc[i][j][3]=0.f; }

  for (int kh = 0; kh < 3; kh++) {
    int kk = kh*96;
    STAGE_FR96(oldbf, m0, sm.st.A);
    for (int it = 0; it < 4; it++) {
      int ncol0 = (grp*4 + it)*128;
      STAGE_FR96(Wgbf, CM_BASE + ncol0, sm.st.Bb);
      __syncthreads();   // drains A (first it) + B loads; prior stores visible
      f32x4 acc[4][4];
      #pragma unroll
      for (int i=0;i<4;i++)
        #pragma unroll
        for (int j=0;j<4;j++){ acc[i][j][0]=0.f;acc[i][j][1]=0.f;acc[i][j][2]=0.f;acc[i][j][3]=0.f; }
      for (int c = 0; c < 3; c++) {
        bf16x8 af[4], bff[4];
        #pragma unroll
        for (int i=0;i<4;i++) af[i]  = *(const bf16x8*)&sm.st.A[c*4096 + (wm*4 + i)*512 + lane*8];
        #pragma unroll
        for (int j=0;j<4;j++) bff[j] = *(const bf16x8*)&sm.st.Bb[c*4096 + (wn*4 + j)*512 + lane*8];
        #pragma unroll
        for (int i=0;i<4;i++)
          #pragma unroll
          for (int j=0;j<4;j++)
            acc[i][j] = __builtin_amdgcn_mfma_f32_16x16x32_bf16(af[i], bff[j], acc[i][j], 0,0,0);
      }
      // kh-partial contraction with z (bg only on last kh)
      int nl = it*2 + wn;
      float bgv[4];
      #pragma unroll
      for (int j=0;j<4;j++)
        bgv[j] = (kh == 2) ? bg[CM_BASE + ncol0 + wn*64 + j*16 + lm] : 0.f;
      #pragma unroll
      for (int i=0;i<4;i++){
        #pragma unroll
        for (int r=0;r<4;r++){
          float zv = sm.st.zl[wm*64 + i*16 + lq*4 + r][nl];
          #pragma unroll
          for (int j=0;j<4;j++)
            yacc[i][j][r] += (acc[i][j][r] + bgv[j]) * zv;
        }
      }
      __syncthreads();   // all LDS reads done before next stage overwrites
    }
  }

  // merge the two wn halves through ylds (overlays staging LDS), then store slice
  if (wn == 1){
    #pragma unroll
    for (int i=0;i<4;i++)
      #pragma unroll
      for (int j=0;j<4;j++)
        #pragma unroll
        for (int r=0;r<4;r++){
          int ml = wm*64 + i*16 + lq*4 + r;
          sm.ylds[ml][j*16 + lm] = yacc[i][j][r];
        }
  }
  __syncthreads();
  if (wn == 0){
    float* dst = ypart + (size_t)grp*(M_*S_);
    #pragma unroll
    for (int i=0;i<4;i++)
      #pragma unroll
      for (int j=0;j<4;j++)
        #pragma unroll
        for (int r=0;r<4;r++){
          int ml = wm*64 + i*16 + lq*4 + r;
          int s = j*16 + lm;
          dst[(size_t)(m0+ml)*S_ + s] = yacc[i][j][r] + sm.ylds[ml][s];
        }
  }
}

// ---------------- finalize: sum slices, write ys (L,B,S), fused loss ----------------
__global__ void k_finalize(const float* __restrict__ ypart, const float* __restrict__ x,
                           float* __restrict__ out, float* __restrict__ lossacc){
  __shared__ float red[256];
  int tid = threadIdx.x;
  float ls = 0.f;
  #pragma unroll
  for (int q = 0; q < 2; q++) {
    int e = blockIdx.x*512 + q*256 + tid;
    int m = e >> 6, s = e & 63;
    int b = m >> 7, l = m & 127;
    float yv = 0.f;
    #pragma unroll 8
    for (int g = 0; g < NSLICE; g++) yv += ypart[(size_t)g*(M_*S_) + e];
    out[1 + (size_t)((l<<4) + b)*S_ + s] = yv;
    float xv = x[((size_t)(b<<8) + 128 + l)*S_ + s];
    float d = yv - xv;
    ls += d*d;
  }
  red[tid] = ls; __syncthreads();
  for (int st = 128; st > 0; st >>= 1) {
    if (tid < st) red[tid] += red[tid+st];
    __syncthreads();
  }
  if (tid == 0) {
    atomicAdd(&lossacc[0], red[0]);
    __threadfence();
    unsigned old = atomicAdd((unsigned*)&lossacc[1], 1u);
    if (old == 255u) {
      float tot = atomicAdd(&lossacc[0], 0.f);   // atomic read (bypass L1)
      out[0] = tot * (1.f / (float)(B_*S_*L_));
    }
  }
}

extern "C" void kernel_launch(void* const* d_in, const int* in_sizes, int n_in,
                              void* d_out, int out_size, void* d_ws, size_t ws_size,
                              hipStream_t stream) {
  const float* x   = (const float*)d_in[0];
  const float* u   = (const float*)d_in[1];
  const float* Ap  = (const float*)d_in[2];
  const float* W0  = (const float*)d_in[3];
  const float* b0  = (const float*)d_in[4];
  const float* W1  = (const float*)d_in[5];
  const float* b1  = (const float*)d_in[6];
  const float* cw  = (const float*)d_in[7];
  const float* cb  = (const float*)d_in[8];
  const float* Wg  = (const float*)d_in[9];
  const float* bg  = (const float*)d_in[10];
  const float* Wdt = (const float*)d_in[11];
  const float* bdt = (const float*)d_in[12];
  float* out = (float*)d_out;

  // Layout: persistent buffers first; region R of fp32 temps (all dead before
  // k_cmfma) is overlaid by ypart (32 slices = 16 MB).
  float* ws    = (float*)d_ws;
  float* zall  = ws;                        // 524288
  float* lossa = zall + 524288;             // 512 (acc, counter)
  bf16_t* oldbf = (bf16_t*)(lossa + 512);   // 294912 f32 slots
  bf16_t* Wgbf  = (bf16_t*)(lossa + 512 + 294912);              // 3548160 slots
  bf16_t* W0bf  = (bf16_t*)(lossa + 512 + 294912 + 3548160);    // 16384 slots
  bf16_t* W1bf  = (bf16_t*)(lossa + 512 + 294912 + 3548160 + 16384);   // 65536 slots
  bf16_t* xbf   = (bf16_t*)(lossa + 512 + 294912 + 3548160 + 16384 + 65536); // 65536 slots
  bf16_t* Hbf   = (bf16_t*)(lossa + 512 + 294912 + 3548160 + 16384 + 65536 + 65536); // 524288 slots
  float* R     = lossa + 512 + 294912 + 3548160 + 16384 + 65536 + 65536 + 524288;
  float* Pp    = R;                         // 524288
  float* dA    = Pp   + 524288;             // 524288
  float* coef  = dA   + 524288;             // 524288
  float* ypart = R;                         // 32*131072 = 4194304, overlays R
  // Pp/dA/coef are dead before k_cmfma (convdelta+bmfma consume them);
  // ypart overlays R and extends into free workspace (as in R5-R14).

  k_prep<<<CVT_BLOCKS + W0_BLOCKS + W1_BLOCKS + XB_BLOCKS, 256, 0, stream>>>(
      Wg, Wgbf, W0, W0bf, W1, W1bf, x, xbf, lossa);
  k_mlp1m<<<dim3(HID_/64, M_/64), 256, 0, stream>>>(xbf, W0bf, b0, Hbf);
  k_mlp2m<<<dim3(N_/64, M_/64), 256, 0, stream>>>(Hbf, W1bf, b1, Pp);
  k_convdelta<<<M_/4, 256, 0, stream>>>(Pp, u, cw, cb, Wg, bg, Wdt, bdt, Ap,
                                        oldbf, dA, coef);
  k_bmfma<<<dim3(64, 16), 256, 0, stream>>>(oldbf, Wgbf, bg, u, coef, dA, Pp, zall);
  k_cmfma<<<dim3(32, 16), 256, 0, stream>>>(oldbf, Wgbf, bg, zall, ypart);
  k_finalize<<<256, 256, 0, stream>>>(ypart, x, out, lossa);
}